// Round 3
// baseline (1529.395 us; speedup 1.0000x reference)
//
#include <hip/hip_runtime.h>
#include <math.h>

// ---------------- model dims ----------------
constexpr int N_NODES = 16384;
constexpr int BGRAPH  = 64;
constexpr int NEDGE   = 524288;
constexpr int SEQ     = 257;           // NPG + cls
constexpr int WDIM    = 256;
constexpr int DFF     = 1024;
constexpr int HID     = 512;
constexpr int MROWS   = BGRAPH * SEQ;  // 16448

// ---------------- ws layout (float offsets) ----------------
constexpr size_t F_Y    = 0;                                   // [N,64] dinv-scaled padded xc
constexpr size_t F_AGG  = F_Y    + (size_t)N_NODES * 64;       // [N,64]
constexpr size_t F_XD   = F_AGG  + (size_t)N_NODES * 64;       // [16448,256] residual stream
constexpr size_t F_H1   = F_XD   + (size_t)MROWS * WDIM;       // [16448,256] post-LN
constexpr size_t F_QKV  = F_H1   + (size_t)MROWS * WDIM;       // [16448,768]
constexpr size_t F_FFB  = F_QKV  + (size_t)MROWS * 3 * WDIM;   // [16448,1024]
constexpr size_t F_CLS  = F_FFB  + (size_t)MROWS * DFF;        // [64,256]
constexpr size_t F_D1   = F_CLS  + (size_t)BGRAPH * WDIM;      // [64,512]
constexpr size_t F_D2   = F_D1   + (size_t)BGRAPH * HID;       // [64,512]
constexpr size_t F_WPAD = F_D2   + (size_t)BGRAPH * HID;       // [64,256] zero-padded gcn_w
constexpr size_t F_DINV = F_WPAD + (size_t)64 * WDIM;          // [N]
constexpr size_t F_END  = F_DINV + (size_t)N_NODES;

typedef __attribute__((ext_vector_type(8))) __bf16 bf16x8;
typedef __attribute__((ext_vector_type(4))) float f32x4;

__device__ __forceinline__ float gelu_f(float x) {
    float u = 0.7978845608028654f * (x + 0.044715f * x * x * x);
    return 0.5f * x * (1.0f + tanhf(u));
}

// ---------------- GCN prelude ----------------
__global__ __launch_bounds__(256) void hist_kernel(const int* __restrict__ col, int* __restrict__ indeg) {
    int e = blockIdx.x * 256 + threadIdx.x;
    atomicAdd(&indeg[col[e]], 1);
}

__global__ __launch_bounds__(1024) void scan_kernel(const int* __restrict__ indeg, int* __restrict__ offs,
                                                    int* __restrict__ cursor, float* __restrict__ dinv) {
    __shared__ int parts[1024];
    int t = threadIdx.x;
    int base = t * 16;
    int loc[16];
    int s = 0;
#pragma unroll
    for (int i = 0; i < 16; ++i) { loc[i] = indeg[base + i]; s += loc[i]; }
    parts[t] = s;
    __syncthreads();
    for (int off = 1; off < 1024; off <<= 1) {
        int v = (t >= off) ? parts[t - off] : 0;
        __syncthreads();
        parts[t] += v;
        __syncthreads();
    }
    int run = (t == 0) ? 0 : parts[t - 1];
#pragma unroll
    for (int i = 0; i < 16; ++i) {
        offs[base + i] = run;
        cursor[base + i] = run;
        dinv[base + i] = rsqrtf((float)loc[i] + 1.0f);  // deg = indeg + self-loop
        run += loc[i];
    }
    if (t == 1023) offs[N_NODES] = run;
}

__global__ __launch_bounds__(256) void fill_kernel(const int* __restrict__ ei, int* __restrict__ cursor,
                                                   int* __restrict__ csr) {
    int e = blockIdx.x * 256 + threadIdx.x;
    int r = ei[e];            // source
    int c = ei[NEDGE + e];    // destination
    int pos = atomicAdd(&cursor[c], 1);
    csr[pos] = r;
}

// xc = [x(32) | sin(p*2^j*pi)(24) | 0(8)], pre-scaled by dinv[node]
__global__ __launch_bounds__(256) void y_kernel(const float* __restrict__ x, const float* __restrict__ p,
                                                const float* __restrict__ dinv, float* __restrict__ y) {
    int idx = blockIdx.x * 256 + threadIdx.x;
    int i = idx >> 6, d = idx & 63;
    float v = 0.f;
    if (d < 32) {
        v = x[i * 32 + d];
    } else if (d < 56) {
        int dd = d - 32;
        int dim = dd >> 3, j = dd & 7;
        v = sinf(p[i * 3 + dim] * (3.14159265358979323846f * (float)(1 << j)));
    }
    y[idx] = dinv[i] * v;
}

// agg[c] = dinv[c] * (y[c] + sum_{in-edges} y[src])   (wave per node)
__global__ __launch_bounds__(256) void agg_kernel(const float* __restrict__ y, const float* __restrict__ dinv,
                                                  const int* __restrict__ offs, const int* __restrict__ csr,
                                                  float* __restrict__ agg) {
    int c = (blockIdx.x * 256 + threadIdx.x) >> 6;
    int lane = threadIdx.x & 63;
    float acc = y[(size_t)c * 64 + lane];
    int s = offs[c], e = offs[c + 1];
    for (int j = s; j < e; ++j) {
        int r = csr[j];
        acc += y[(size_t)r * 64 + lane];
    }
    agg[(size_t)c * 64 + lane] = dinv[c] * acc;
}

__global__ __launch_bounds__(256) void wpad_kernel(const float* __restrict__ w, float* __restrict__ wp) {
    int idx = blockIdx.x * 256 + threadIdx.x;
    wp[idx] = (idx < 56 * 256) ? w[idx] : 0.f;
}

__global__ __launch_bounds__(256) void cls_write(const float* __restrict__ tok, float* __restrict__ xd) {
    xd[(size_t)blockIdx.x * SEQ * WDIM + threadIdx.x] = tok[threadIdx.x];
}

// ---------------- LayerNorm (one row of 256 per block) ----------------
__global__ __launch_bounds__(256) void ln_kernel(const float* __restrict__ in, float* __restrict__ out,
                                                 const float* __restrict__ g, const float* __restrict__ be,
                                                 int rin_mul, int rout_mul) {
    int t = threadIdx.x;
    size_t ib = (size_t)blockIdx.x * rin_mul * WDIM;
    size_t ob = (size_t)blockIdx.x * rout_mul * WDIM;
    float v = in[ib + t];
    float s = v, ss = v * v;
#pragma unroll
    for (int off = 1; off < 64; off <<= 1) { s += __shfl_xor(s, off); ss += __shfl_xor(ss, off); }
    __shared__ float red[8];
    if ((t & 63) == 0) { red[t >> 6] = s; red[4 + (t >> 6)] = ss; }
    __syncthreads();
    s = red[0] + red[1] + red[2] + red[3];
    ss = red[4] + red[5] + red[6] + red[7];
    float mean = s * 0.00390625f;
    float var = ss * 0.00390625f - mean * mean;
    float rs = rsqrtf(var + 1e-5f);
    out[ob + t] = (v - mean) * rs * g[t] + be[t];
}

// ---------------- weight transpose+cast: W[K][N] fp32 -> Wt[N][K] bf16 ----------------
__global__ __launch_bounds__(256) void tcast_kernel(const float* __restrict__ W, __bf16* __restrict__ Wt,
                                                    int K, int N) {
    __shared__ __bf16 T[64][65];
    int t = threadIdx.x;
    int k0 = blockIdx.x << 6, n0 = blockIdx.y << 6;
#pragma unroll
    for (int i = 0; i < 16; ++i) {
        int idx = t + i * 256;
        int k = idx >> 6, n = idx & 63;
        T[k][n] = (__bf16)W[(size_t)(k0 + k) * N + n0 + n];
    }
    __syncthreads();
#pragma unroll
    for (int i = 0; i < 16; ++i) {
        int idx = t + i * 256;
        int n = idx >> 6, k = idx & 63;
        Wt[(size_t)(n0 + n) * K + k0 + k] = T[k][n];
    }
}

// ---------------- bf16 MFMA GEMM: C[M,N] = epi(A[M,K](fp32) @ Bt[N,K](bf16) + bias) ----------------
template <int ACT, bool RESID>
__global__ __launch_bounds__(256) void gemm_mfma(const float* __restrict__ A, int lda,
                                                 const __bf16* __restrict__ Bt,
                                                 const float* __restrict__ bias,
                                                 float* __restrict__ C, int ldc,
                                                 int Ktot, int Mrows) {
    __shared__ __bf16 As[128 * 32];
    __shared__ __bf16 Bs[128 * 32];
    int t = threadIdx.x;
    int m0 = blockIdx.x << 7, n0 = blockIdx.y << 7;
    int w = t >> 6, L = t & 63;
    int wm = w >> 1, wn = w & 1;

    int srow = t >> 1, skc = (t & 1) << 4;
    const float* ap = A + (size_t)(m0 + srow) * lda + skc;
    const __bf16* bp = Bt + (size_t)(n0 + srow) * Ktot + skc;

    int lc = L & 15, lq = L >> 4;
    int a_base = (wm * 64 + lc) * 32 + lq * 8;
    int b_base = (wn * 64 + lc) * 32 + lq * 8;

    f32x4 acc[4][4] = {};

    for (int k0 = 0; k0 < Ktot; k0 += 32) {
        f32x4 a0 = *(const f32x4*)(ap + k0);
        f32x4 a1 = *(const f32x4*)(ap + k0 + 4);
        f32x4 a2 = *(const f32x4*)(ap + k0 + 8);
        f32x4 a3 = *(const f32x4*)(ap + k0 + 12);
        f32x4 b0 = *(const f32x4*)(bp + k0);       // 8 bf16
        f32x4 b1 = *(const f32x4*)(bp + k0 + 8);   // 8 bf16
        __syncthreads();
        bf16x8 pa0, pa1;
        pa0[0] = (__bf16)a0.x; pa0[1] = (__bf16)a0.y; pa0[2] = (__bf16)a0.z; pa0[3] = (__bf16)a0.w;
        pa0[4] = (__bf16)a1.x; pa0[5] = (__bf16)a1.y; pa0[6] = (__bf16)a1.z; pa0[7] = (__bf16)a1.w;
        pa1[0] = (__bf16)a2.x; pa1[1] = (__bf16)a2.y; pa1[2] = (__bf16)a2.z; pa1[3] = (__bf16)a2.w;
        pa1[4] = (__bf16)a3.x; pa1[5] = (__bf16)a3.y; pa1[6] = (__bf16)a3.z; pa1[7] = (__bf16)a3.w;
        *(bf16x8*)&As[srow * 32 + skc]     = pa0;
        *(bf16x8*)&As[srow * 32 + skc + 8] = pa1;
        *(f32x4*)&Bs[srow * 32 + skc]     = b0;
        *(f32x4*)&Bs[srow * 32 + skc + 8] = b1;
        __syncthreads();
        bf16x8 af[4], bf[4];
#pragma unroll
        for (int i = 0; i < 4; ++i) {
            af[i] = *(const bf16x8*)&As[a_base + i * 512];
            bf[i] = *(const bf16x8*)&Bs[b_base + i * 512];
        }
#pragma unroll
        for (int mt = 0; mt < 4; ++mt)
#pragma unroll
            for (int nt = 0; nt < 4; ++nt)
                acc[mt][nt] = __builtin_amdgcn_mfma_f32_16x16x32_bf16(af[mt], bf[nt], acc[mt][nt], 0, 0, 0);
    }

#pragma unroll
    for (int mt = 0; mt < 4; ++mt) {
        int gm_base = m0 + wm * 64 + mt * 16 + lq * 4;
#pragma unroll
        for (int nt = 0; nt < 4; ++nt) {
            int gn = n0 + wn * 64 + nt * 16 + lc;
            float bv = bias[gn];
#pragma unroll
            for (int r = 0; r < 4; ++r) {
                int gm = gm_base + r;
                if (gm >= Mrows) continue;
                float v = acc[mt][nt][r] + bv;
                if (ACT == 1) v = gelu_f(v);
                float* cp = C + (size_t)gm * ldc + gn;
                if (RESID) v += *cp;
                *cp = v;
            }
        }
    }
}

// ---------------- fused attention: one block per (32-row q-tile, graph, head) ----------------
// grid dim3(9, 512). LDS: Q tile, K/V staged in two halves, full 32x257 score rows.
// Softmax mask: q==0 -> all allowed, else k<=q. O written into dead Q slice of qkv.
__global__ __launch_bounds__(256) void attn_fused(float* __restrict__ qkvb) {
    __shared__ float Qs[32][36];
    __shared__ float KVs[129][36];
    __shared__ float Ps[32][260];
    int qt = blockIdx.x;           // 0..8
    int bb = blockIdx.y;           // 0..511
    int b = bb >> 3, h = bb & 7;
    int q0 = qt * 32;
    const float* base = qkvb + (size_t)(b * SEQ) * 768 + h * 32;  // Q at +0, K at +256, V at +512
    int t = threadIdx.x;
    const float scale = 0.17677669529663687f;  // 1/sqrt(32)

    // load Q tile (zero-padded past SEQ)
    {
        int r = t >> 3, seg = (t & 7) * 4;
        int gq = q0 + r;
        float4 v = {0.f, 0.f, 0.f, 0.f};
        if (gq < SEQ) v = *(const float4*)(base + (size_t)gq * 768 + seg);
        *(float4*)&Qs[r][seg] = v;
    }

    int tm = (t >> 4) * 2;   // 2 rows per thread
    int tn = t & 15;         // cols tn + 16*j per k-tile

    // ---- phase 1: S = scale * Q K^T, K staged in halves ----
    for (int half = 0; half < 2; ++half) {
        int krow0 = half * 128;
        int nrows = half ? 129 : 128;     // half 1 includes row 256
        __syncthreads();
        for (int idx = t; idx < nrows * 8; idx += 256) {
            int r = idx >> 3, seg = (idx & 7) * 4;
            *(float4*)&KVs[r][seg] = *(const float4*)(base + 256 + (size_t)(krow0 + r) * 768 + seg);
        }
        __syncthreads();
        for (int kt = 0; kt < 2; ++kt) {
            int n0 = kt * 64;
            float acc[2][4] = {};
#pragma unroll
            for (int kd = 0; kd < 32; kd += 4) {
                float4 a0 = *(const float4*)&Qs[tm][kd];
                float4 a1 = *(const float4*)&Qs[tm + 1][kd];
                float4 b0 = *(const float4*)&KVs[n0 + tn][kd];
                float4 b1 = *(const float4*)&KVs[n0 + tn + 16][kd];
                float4 b2 = *(const float4*)&KVs[n0 + tn + 32][kd];
                float4 b3 = *(const float4*)&KVs[n0 + tn + 48][kd];
                acc[0][0] += a0.x * b0.x + a0.y * b0.y + a0.z * b0.z + a0.w * b0.w;
                acc[0][1] += a0.x * b1.x + a0.y * b1.y + a0.z * b1.z + a0.w * b1.w;
                acc[0][2] += a0.x * b2.x + a0.y * b2.y + a0.z * b2.z + a0.w * b2.w;
                acc[0][3] += a0.x * b3.x + a0.y * b3.y + a0.z * b3.z + a0.w * b3.w;
                acc[1][0] += a1.x * b0.x + a1.y * b0.y + a1.z * b0.z + a1.w * b0.w;
                acc[1][1] += a1.x * b1.x + a1.y * b1.y + a1.z * b1.z + a1.w * b1.w;
                acc[1][2] += a1.x * b2.x + a1.y * b2.y + a1.z * b2.z + a1.w * b2.w;
                acc[1][3] += a1.x * b3.x + a1.y * b3.y + a1.z * b3.z + a1.w * b3.w;
            }
#pragma unroll
            for (int j = 0; j < 4; ++j) {
                int col = krow0 + n0 + tn + 16 * j;
                Ps[tm][col]     = acc[0][j] * scale;
                Ps[tm + 1][col] = acc[1][j] * scale;
            }
        }
        if (half == 1 && t < 32) {  // col 256 (K row 256 is KVs[128])
            float s = 0.f;
#pragma unroll
            for (int d = 0; d < 32; ++d) s += Qs[t][d] * KVs[128][d];
            Ps[t][256] = s * scale;
        }
    }
    __syncthreads();

    // ---- phase 2: masked softmax, wave per 8 rows ----
    {
        int wv = t >> 6, lane = t & 63;
        for (int rr = 0; rr < 8; ++rr) {
            int r = wv * 8 + rr;
            int gq = q0 + r;
            float xv[5];
            float m = -3.0e38f;
#pragma unroll
            for (int j = 0; j < 5; ++j) {
                int k = lane + j * 64;
                bool ok = (k < SEQ) && (gq == 0 || k <= gq);
                xv[j] = ok ? Ps[r][k] : -3.0e38f;
                m = fmaxf(m, xv[j]);
            }
#pragma unroll
            for (int off = 1; off < 64; off <<= 1) m = fmaxf(m, __shfl_xor(m, off));
            float s = 0.f;
#pragma unroll
            for (int j = 0; j < 5; ++j) { xv[j] = expf(xv[j] - m); s += xv[j]; }
#pragma unroll
            for (int off = 1; off < 64; off <<= 1) s += __shfl_xor(s, off);
            float inv = 1.0f / s;
#pragma unroll
            for (int j = 0; j < 5; ++j) {
                int k = lane + j * 64;
                if (k < SEQ) Ps[r][k] = xv[j] * inv;
            }
        }
    }

    // ---- phase 3: O = P V, V staged in halves ----
    float oacc[2][2] = {{0.f, 0.f}, {0.f, 0.f}};
    int vd = (t & 15) * 2;
    for (int half = 0; half < 2; ++half) {
        int krow0 = half * 128;
        int nrows = half ? 129 : 128;
        __syncthreads();
        for (int idx = t; idx < nrows * 8; idx += 256) {
            int r = idx >> 3, seg = (idx & 7) * 4;
            *(float4*)&KVs[r][seg] = *(const float4*)(base + 512 + (size_t)(krow0 + r) * 768 + seg);
        }
        __syncthreads();
        for (int k = 0; k < 128; k += 4) {
            float4 p0 = *(const float4*)&Ps[tm][krow0 + k];
            float4 p1 = *(const float4*)&Ps[tm + 1][krow0 + k];
            float2 v0 = *(const float2*)&KVs[k][vd];
            float2 v1 = *(const float2*)&KVs[k + 1][vd];
            float2 v2 = *(const float2*)&KVs[k + 2][vd];
            float2 v3 = *(const float2*)&KVs[k + 3][vd];
            oacc[0][0] += p0.x * v0.x + p0.y * v1.x + p0.z * v2.x + p0.w * v3.x;
            oacc[0][1] += p0.x * v0.y + p0.y * v1.y + p0.z * v2.y + p0.w * v3.y;
            oacc[1][0] += p1.x * v0.x + p1.y * v1.x + p1.z * v2.x + p1.w * v3.x;
            oacc[1][1] += p1.x * v0.y + p1.y * v1.y + p1.z * v2.y + p1.w * v3.y;
        }
        if (half == 1) {  // k = 256 tail
            float p0 = Ps[tm][256], p1 = Ps[tm + 1][256];
            float2 vv = *(const float2*)&KVs[128][vd];
            oacc[0][0] += p0 * vv.x; oacc[0][1] += p0 * vv.y;
            oacc[1][0] += p1 * vv.x; oacc[1][1] += p1 * vv.y;
        }
    }

    // write O into Q slice (dead)
    float* ob = qkvb + (size_t)(b * SEQ) * 768 + h * 32;
#pragma unroll
    for (int i = 0; i < 2; ++i) {
        int gq = q0 + tm + i;
        if (gq < SEQ) {
            float2 r;
            r.x = oacc[i][0]; r.y = oacc[i][1];
            *(float2*)(ob + (size_t)gq * 768 + vd) = r;
        }
    }
}

// ---------------- fp32 tiled GEMM (kept for GCN projection) ----------------
template <int ACT, bool RESID, bool REMAP>
__global__ __launch_bounds__(256) void gemm_std(const float* __restrict__ A, int lda,
                                                const float* __restrict__ Bw, int ldb,
                                                const float* __restrict__ bias,
                                                float* __restrict__ C, int ldc, int Ktot) {
    int t = threadIdx.x;
    int m0 = blockIdx.x << 6, n0 = blockIdx.y << 6;
    __shared__ float As[16][68];
    __shared__ float Bs[16][64];
    int arow = t >> 2, akk = (t & 3) << 2;
    int bk = t >> 4, bn = (t & 15) << 2;
    int tm = (t >> 4) << 2, tn = (t & 15) << 2;
    float acc[4][4] = {};
    const float* ap = A + (size_t)(m0 + arow) * lda + akk;
    const float* bp = Bw + (size_t)bk * ldb + n0 + bn;
    for (int k0 = 0; k0 < Ktot; k0 += 16) {
        float4 av = *(const float4*)(ap + k0);
        float4 bv = *(const float4*)(bp + (size_t)k0 * ldb);
        __syncthreads();
        As[akk + 0][arow] = av.x; As[akk + 1][arow] = av.y;
        As[akk + 2][arow] = av.z; As[akk + 3][arow] = av.w;
        *(float4*)&Bs[bk][bn] = bv;
        __syncthreads();
#pragma unroll
        for (int k = 0; k < 16; ++k) {
            float4 a = *(const float4*)&As[k][tm];
            float4 b = *(const float4*)&Bs[k][tn];
            acc[0][0] += a.x * b.x; acc[0][1] += a.x * b.y; acc[0][2] += a.x * b.z; acc[0][3] += a.x * b.w;
            acc[1][0] += a.y * b.x; acc[1][1] += a.y * b.y; acc[1][2] += a.y * b.z; acc[1][3] += a.y * b.w;
            acc[2][0] += a.z * b.x; acc[2][1] += a.z * b.y; acc[2][2] += a.z * b.z; acc[2][3] += a.z * b.w;
            acc[3][0] += a.w * b.x; acc[3][1] += a.w * b.y; acc[3][2] += a.w * b.z; acc[3][3] += a.w * b.w;
        }
    }
#pragma unroll
    for (int i = 0; i < 4; ++i) {
        int gm = m0 + tm + i;
        int orow = REMAP ? (gm + (gm >> 8) + 1) : gm;  // node -> xd row (skip cls slots)
        float* cp = C + (size_t)orow * ldc + n0 + tn;
        float4 r;
        r.x = acc[i][0] + bias[n0 + tn + 0];
        r.y = acc[i][1] + bias[n0 + tn + 1];
        r.z = acc[i][2] + bias[n0 + tn + 2];
        r.w = acc[i][3] + bias[n0 + tn + 3];
        if (ACT == 1) { r.x = gelu_f(r.x); r.y = gelu_f(r.y); r.z = gelu_f(r.z); r.w = gelu_f(r.w); }
        if (ACT == 2) { r.x = fmaxf(r.x, 0.f); r.y = fmaxf(r.y, 0.f); r.z = fmaxf(r.z, 0.f); r.w = fmaxf(r.w, 0.f); }
        if (RESID) {
            float4 o = *(const float4*)cp;
            r.x += o.x; r.y += o.y; r.z += o.z; r.w += o.w;
        }
        *(float4*)cp = r;
    }
}

// ---------------- decoder FC: grid (sample, out-chunk), 4 waves split K ----------------
template <int K, int NOUT>
__global__ __launch_bounds__(256) void dec_fc2(const float* __restrict__ in, const float* __restrict__ w,
                                               const float* __restrict__ bia, float* __restrict__ out) {
    __shared__ float rowbuf[K];
    __shared__ float part[4][64];
    int b = blockIdx.x, c = blockIdx.y, t = threadIdx.x;
    for (int i = t; i < K; i += 256) rowbuf[i] = in[(size_t)b * K + i];
    __syncthreads();
    int lane = t & 63, wv = t >> 6;
    int n = c * 64 + lane;
    const int KQ = K / 4;
    const float* wp = w + (size_t)(wv * KQ) * NOUT + n;
    float s = 0.f;
#pragma unroll 8
    for (int k = 0; k < KQ; ++k) s += rowbuf[wv * KQ + k] * wp[(size_t)k * NOUT];
    part[wv][lane] = s;
    __syncthreads();
    if (wv == 0) {
        float r = part[0][lane] + part[1][lane] + part[2][lane] + part[3][lane] + bia[n];
        out[(size_t)b * NOUT + n] = fmaxf(r, 0.f);
    }
}

// ---------------- launch ----------------
extern "C" void kernel_launch(void* const* d_in, const int* in_sizes, int n_in,
                              void* d_out, int out_size, void* d_ws, size_t ws_size,
                              hipStream_t stream) {
    const float* x         = (const float*)d_in[0];
    const float* p         = (const float*)d_in[1];
    const int*   ei        = (const int*)d_in[2];
    const float* gcn_w     = (const float*)d_in[4];
    const float* gcn_b     = (const float*)d_in[5];
    const float* cls_tok   = (const float*)d_in[6];
    const float* ln_pre_s  = (const float*)d_in[7];
    const float* ln_pre_b  = (const float*)d_in[8];
    const float* norm1_s   = (const float*)d_in[9];
    const float* norm1_b   = (const float*)d_in[10];
    const float* in_proj_w = (const float*)d_in[11];
    const float* in_proj_b = (const float*)d_in[12];
    const float* out_proj_w= (const float*)d_in[13];
    const float* out_proj_b= (const float*)d_in[14];
    const float* norm2_s   = (const float*)d_in[15];
    const float* norm2_b   = (const float*)d_in[16];
    const float* ff_w1     = (const float*)d_in[17];
    const float* ff_b1     = (const float*)d_in[18];
    const float* ff_w2     = (const float*)d_in[19];
    const float* ff_b2     = (const float*)d_in[20];
    const float* ln_post_s = (const float*)d_in[21];
    const float* ln_post_b = (const float*)d_in[22];
    const float* dec_w1    = (const float*)d_in[23];
    const float* dec_b1    = (const float*)d_in[24];
    const float* dec_w2    = (const float*)d_in[25];
    const float* dec_b2    = (const float*)d_in[26];
    const float* dec_w3    = (const float*)d_in[27];
    const float* dec_b3    = (const float*)d_in[28];

    float* ws   = (float*)d_ws;
    float* y    = ws + F_Y;
    float* agg  = ws + F_AGG;
    float* xd   = ws + F_XD;
    float* h1   = ws + F_H1;
    float* qkv  = ws + F_QKV;
    float* ffb  = ws + F_FFB;
    float* cls  = ws + F_CLS;
    float* dd1  = ws + F_D1;
    float* dd2  = ws + F_D2;
    float* wpad = ws + F_WPAD;
    float* dinv = ws + F_DINV;
    int* ibase  = (int*)(ws + F_END);
    int* indeg  = ibase;
    int* offs   = ibase + N_NODES;
    int* cursor = offs + N_NODES + 1;
    int* csr    = cursor + N_NODES;
    __bf16* wtb = (__bf16*)(csr + NEDGE);
    __bf16* wt_in  = wtb;                         // 2 x 768*256
    __bf16* wt_out = wt_in  + 2 * 768 * 256;      // 2 x 256*256
    __bf16* wt_f1  = wt_out + 2 * 256 * 256;      // 2 x 1024*256
    __bf16* wt_f2  = wt_f1  + 2 * 1024 * 256;     // 2 x 256*1024

    // GCN prelude
    hipMemsetAsync(indeg, 0, N_NODES * sizeof(int), stream);
    hist_kernel<<<NEDGE / 256, 256, 0, stream>>>(ei + NEDGE, indeg);
    scan_kernel<<<1, 1024, 0, stream>>>(indeg, offs, cursor, dinv);
    fill_kernel<<<NEDGE / 256, 256, 0, stream>>>(ei, cursor, csr);
    y_kernel<<<N_NODES * 64 / 256, 256, 0, stream>>>(x, p, dinv, y);
    agg_kernel<<<N_NODES / 4, 256, 0, stream>>>(y, dinv, offs, csr, agg);
    wpad_kernel<<<64, 256, 0, stream>>>(gcn_w, wpad);

    // weight transpose+cast (once per call)
    for (int l = 0; l < 2; ++l) {
        tcast_kernel<<<dim3(4, 12), 256, 0, stream>>>(in_proj_w + (size_t)l * 256 * 768,
                                                      wt_in + (size_t)l * 768 * 256, 256, 768);
        tcast_kernel<<<dim3(4, 4), 256, 0, stream>>>(out_proj_w + (size_t)l * 256 * 256,
                                                     wt_out + (size_t)l * 256 * 256, 256, 256);
        tcast_kernel<<<dim3(4, 16), 256, 0, stream>>>(ff_w1 + (size_t)l * 256 * 1024,
                                                      wt_f1 + (size_t)l * 1024 * 256, 256, 1024);
        tcast_kernel<<<dim3(16, 4), 256, 0, stream>>>(ff_w2 + (size_t)l * 1024 * 256,
                                                      wt_f2 + (size_t)l * 256 * 1024, 1024, 256);
    }

    // GCN matmul -> xd rows (remapped past cls slots), fp32
    gemm_std<0, false, true><<<dim3(256, 4), 256, 0, stream>>>(agg, 64, wpad, 256, gcn_b, xd, 256, 64);
    cls_write<<<64, 256, 0, stream>>>(cls_tok, xd);
    ln_kernel<<<MROWS, 256, 0, stream>>>(xd, xd, ln_pre_s, ln_pre_b, 1, 1);

    const int MB = (MROWS + 127) / 128;  // 129
    for (int l = 0; l < 2; ++l) {
        ln_kernel<<<MROWS, 256, 0, stream>>>(xd, h1, norm1_s + l * WDIM, norm1_b + l * WDIM, 1, 1);
        gemm_mfma<0, false><<<dim3(MB, 6), 256, 0, stream>>>(
            h1, 256, wt_in + (size_t)l * 768 * 256, in_proj_b + l * 768, qkv, 768, 256, MROWS);
        attn_fused<<<dim3(9, 512), 256, 0, stream>>>(qkv);
        gemm_mfma<0, true><<<dim3(MB, 2), 256, 0, stream>>>(
            qkv, 768, wt_out + (size_t)l * 256 * 256, out_proj_b + l * WDIM, xd, 256, 256, MROWS);
        ln_kernel<<<MROWS, 256, 0, stream>>>(xd, h1, norm2_s + l * WDIM, norm2_b + l * WDIM, 1, 1);
        gemm_mfma<1, false><<<dim3(MB, 8), 256, 0, stream>>>(
            h1, 256, wt_f1 + (size_t)l * 1024 * 256, ff_b1 + l * DFF, ffb, 1024, 256, MROWS);
        gemm_mfma<1, true><<<dim3(MB, 2), 256, 0, stream>>>(
            ffb, 1024, wt_f2 + (size_t)l * 256 * 1024, ff_b2 + l * WDIM, xd, 256, 1024, MROWS);
    }

    // cls extract + ln_post + decoder
    ln_kernel<<<BGRAPH, 256, 0, stream>>>(xd, cls, ln_post_s, ln_post_b, SEQ, 1);
    dec_fc2<256, 512><<<dim3(BGRAPH, 8), 256, 0, stream>>>(cls, dec_w1, dec_b1, dd1);
    dec_fc2<512, 512><<<dim3(BGRAPH, 8), 256, 0, stream>>>(dd1, dec_w2, dec_b2, dd2);
    dec_fc2<512, 64><<<dim3(BGRAPH, 1), 256, 0, stream>>>(dd2, dec_w3, dec_b3, (float*)d_out);
}

// Round 4
// 852.205 us; speedup vs baseline: 1.7946x; 1.7946x over previous
//
#include <hip/hip_runtime.h>
#include <math.h>

// ---------------- model dims ----------------
constexpr int N_NODES = 16384;
constexpr int BGRAPH  = 64;
constexpr int NEDGE   = 524288;
constexpr int SEQ     = 257;           // NPG + cls
constexpr int WDIM    = 256;
constexpr int DFF     = 1024;
constexpr int HID     = 512;
constexpr int MROWS   = BGRAPH * SEQ;  // 16448

// ---------------- ws layout (float offsets) ----------------
constexpr size_t F_Y    = 0;                                   // [N,64] dinv-scaled padded xc
constexpr size_t F_AGG  = F_Y    + (size_t)N_NODES * 64;       // [N,64]
constexpr size_t F_XD   = F_AGG  + (size_t)N_NODES * 64;       // [16448,256] residual stream
constexpr size_t F_H1   = F_XD   + (size_t)MROWS * WDIM;       // [16448,256] post-LN
constexpr size_t F_QKV  = F_H1   + (size_t)MROWS * WDIM;       // [16448,768]
constexpr size_t F_FFB  = F_QKV  + (size_t)MROWS * 3 * WDIM;   // [16448,1024]
constexpr size_t F_CLS  = F_FFB  + (size_t)MROWS * DFF;        // [64,256]
constexpr size_t F_D1   = F_CLS  + (size_t)BGRAPH * WDIM;      // [64,512]
constexpr size_t F_D2   = F_D1   + (size_t)BGRAPH * HID;       // [64,512]
constexpr size_t F_WPAD = F_D2   + (size_t)BGRAPH * HID;       // [64,256] zero-padded gcn_w
constexpr size_t F_DINV = F_WPAD + (size_t)64 * WDIM;          // [N]
constexpr size_t F_END  = F_DINV + (size_t)N_NODES;

typedef __attribute__((ext_vector_type(8))) __bf16 bf16x8;
typedef __attribute__((ext_vector_type(4))) float f32x4;

__device__ __forceinline__ float gelu_f(float x) {
    float u = 0.7978845608028654f * (x + 0.044715f * x * x * x);
    return 0.5f * x * (1.0f + tanhf(u));
}

// ---------------- GCN prelude ----------------
__global__ __launch_bounds__(256) void hist_kernel(const int* __restrict__ col, int* __restrict__ indeg) {
    int e = blockIdx.x * 256 + threadIdx.x;
    atomicAdd(&indeg[col[e]], 1);
}

__global__ __launch_bounds__(1024) void scan_kernel(const int* __restrict__ indeg, int* __restrict__ offs,
                                                    int* __restrict__ cursor, float* __restrict__ dinv) {
    __shared__ int parts[1024];
    int t = threadIdx.x;
    int base = t * 16;
    int loc[16];
    int s = 0;
#pragma unroll
    for (int i = 0; i < 16; ++i) { loc[i] = indeg[base + i]; s += loc[i]; }
    parts[t] = s;
    __syncthreads();
    for (int off = 1; off < 1024; off <<= 1) {
        int v = (t >= off) ? parts[t - off] : 0;
        __syncthreads();
        parts[t] += v;
        __syncthreads();
    }
    int run = (t == 0) ? 0 : parts[t - 1];
#pragma unroll
    for (int i = 0; i < 16; ++i) {
        offs[base + i] = run;
        cursor[base + i] = run;
        dinv[base + i] = rsqrtf((float)loc[i] + 1.0f);  // deg = indeg + self-loop
        run += loc[i];
    }
    if (t == 1023) offs[N_NODES] = run;
}

__global__ __launch_bounds__(256) void fill_kernel(const int* __restrict__ ei, int* __restrict__ cursor,
                                                   int* __restrict__ csr) {
    int e = blockIdx.x * 256 + threadIdx.x;
    int r = ei[e];            // source
    int c = ei[NEDGE + e];    // destination
    int pos = atomicAdd(&cursor[c], 1);
    csr[pos] = r;
}

// xc = [x(32) | sin(p*2^j*pi)(24) | 0(8)], pre-scaled by dinv[node]
__global__ __launch_bounds__(256) void y_kernel(const float* __restrict__ x, const float* __restrict__ p,
                                                const float* __restrict__ dinv, float* __restrict__ y) {
    int idx = blockIdx.x * 256 + threadIdx.x;
    int i = idx >> 6, d = idx & 63;
    float v = 0.f;
    if (d < 32) {
        v = x[i * 32 + d];
    } else if (d < 56) {
        int dd = d - 32;
        int dim = dd >> 3, j = dd & 7;
        v = sinf(p[i * 3 + dim] * (3.14159265358979323846f * (float)(1 << j)));
    }
    y[idx] = dinv[i] * v;
}

// agg[c] = dinv[c] * (y[c] + sum_{in-edges} y[src])   (wave per node)
__global__ __launch_bounds__(256) void agg_kernel(const float* __restrict__ y, const float* __restrict__ dinv,
                                                  const int* __restrict__ offs, const int* __restrict__ csr,
                                                  float* __restrict__ agg) {
    int c = (blockIdx.x * 256 + threadIdx.x) >> 6;
    int lane = threadIdx.x & 63;
    float acc = y[(size_t)c * 64 + lane];
    int s = offs[c], e = offs[c + 1];
    for (int j = s; j < e; ++j) {
        int r = csr[j];
        acc += y[(size_t)r * 64 + lane];
    }
    agg[(size_t)c * 64 + lane] = dinv[c] * acc;
}

__global__ __launch_bounds__(256) void wpad_kernel(const float* __restrict__ w, float* __restrict__ wp) {
    int idx = blockIdx.x * 256 + threadIdx.x;
    wp[idx] = (idx < 56 * 256) ? w[idx] : 0.f;
}

__global__ __launch_bounds__(256) void cls_write(const float* __restrict__ tok, float* __restrict__ xd) {
    xd[(size_t)blockIdx.x * SEQ * WDIM + threadIdx.x] = tok[threadIdx.x];
}

// ---------------- LayerNorm (one row of 256 per block) ----------------
__global__ __launch_bounds__(256) void ln_kernel(const float* __restrict__ in, float* __restrict__ out,
                                                 const float* __restrict__ g, const float* __restrict__ be,
                                                 int rin_mul, int rout_mul) {
    int t = threadIdx.x;
    size_t ib = (size_t)blockIdx.x * rin_mul * WDIM;
    size_t ob = (size_t)blockIdx.x * rout_mul * WDIM;
    float v = in[ib + t];
    float s = v, ss = v * v;
#pragma unroll
    for (int off = 1; off < 64; off <<= 1) { s += __shfl_xor(s, off); ss += __shfl_xor(ss, off); }
    __shared__ float red[8];
    if ((t & 63) == 0) { red[t >> 6] = s; red[4 + (t >> 6)] = ss; }
    __syncthreads();
    s = red[0] + red[1] + red[2] + red[3];
    ss = red[4] + red[5] + red[6] + red[7];
    float mean = s * 0.00390625f;
    float var = ss * 0.00390625f - mean * mean;
    float rs = rsqrtf(var + 1e-5f);
    out[ob + t] = (v - mean) * rs * g[t] + be[t];
}

// ---------------- weight transpose+cast: W[K][N] fp32 -> Wt[N][K] bf16 ----------------
__global__ __launch_bounds__(256) void tcast_kernel(const float* __restrict__ W, __bf16* __restrict__ Wt,
                                                    int K, int N) {
    __shared__ __bf16 T[64][65];
    int t = threadIdx.x;
    int k0 = blockIdx.x << 6, n0 = blockIdx.y << 6;
#pragma unroll
    for (int i = 0; i < 16; ++i) {
        int idx = t + i * 256;
        int k = idx >> 6, n = idx & 63;
        T[k][n] = (__bf16)W[(size_t)(k0 + k) * N + n0 + n];
    }
    __syncthreads();
#pragma unroll
    for (int i = 0; i < 16; ++i) {
        int idx = t + i * 256;
        int n = idx >> 6, k = idx & 63;
        Wt[(size_t)(n0 + n) * K + k0 + k] = T[k][n];
    }
}

// ---------------- bf16 MFMA GEMM: C[M,N] = epi(A[M,K](fp32) @ Bt[N,K](bf16) + bias) ----------------
template <int ACT, bool RESID>
__global__ __launch_bounds__(256) void gemm_mfma(const float* __restrict__ A, int lda,
                                                 const __bf16* __restrict__ Bt,
                                                 const float* __restrict__ bias,
                                                 float* __restrict__ C, int ldc,
                                                 int Ktot, int Mrows) {
    __shared__ __bf16 As[128 * 32];
    __shared__ __bf16 Bs[128 * 32];
    int t = threadIdx.x;
    int m0 = blockIdx.x << 7, n0 = blockIdx.y << 7;
    int w = t >> 6, L = t & 63;
    int wm = w >> 1, wn = w & 1;

    int srow = t >> 1, skc = (t & 1) << 4;
    const float* ap = A + (size_t)(m0 + srow) * lda + skc;
    const __bf16* bp = Bt + (size_t)(n0 + srow) * Ktot + skc;

    int lc = L & 15, lq = L >> 4;
    int a_base = (wm * 64 + lc) * 32 + lq * 8;
    int b_base = (wn * 64 + lc) * 32 + lq * 8;

    f32x4 acc[4][4] = {};

    for (int k0 = 0; k0 < Ktot; k0 += 32) {
        f32x4 a0 = *(const f32x4*)(ap + k0);
        f32x4 a1 = *(const f32x4*)(ap + k0 + 4);
        f32x4 a2 = *(const f32x4*)(ap + k0 + 8);
        f32x4 a3 = *(const f32x4*)(ap + k0 + 12);
        f32x4 b0 = *(const f32x4*)(bp + k0);       // 8 bf16
        f32x4 b1 = *(const f32x4*)(bp + k0 + 8);   // 8 bf16
        __syncthreads();
        bf16x8 pa0, pa1;
        pa0[0] = (__bf16)a0.x; pa0[1] = (__bf16)a0.y; pa0[2] = (__bf16)a0.z; pa0[3] = (__bf16)a0.w;
        pa0[4] = (__bf16)a1.x; pa0[5] = (__bf16)a1.y; pa0[6] = (__bf16)a1.z; pa0[7] = (__bf16)a1.w;
        pa1[0] = (__bf16)a2.x; pa1[1] = (__bf16)a2.y; pa1[2] = (__bf16)a2.z; pa1[3] = (__bf16)a2.w;
        pa1[4] = (__bf16)a3.x; pa1[5] = (__bf16)a3.y; pa1[6] = (__bf16)a3.z; pa1[7] = (__bf16)a3.w;
        *(bf16x8*)&As[srow * 32 + skc]     = pa0;
        *(bf16x8*)&As[srow * 32 + skc + 8] = pa1;
        *(f32x4*)&Bs[srow * 32 + skc]     = b0;
        *(f32x4*)&Bs[srow * 32 + skc + 8] = b1;
        __syncthreads();
        bf16x8 af[4], bf[4];
#pragma unroll
        for (int i = 0; i < 4; ++i) {
            af[i] = *(const bf16x8*)&As[a_base + i * 512];
            bf[i] = *(const bf16x8*)&Bs[b_base + i * 512];
        }
#pragma unroll
        for (int mt = 0; mt < 4; ++mt)
#pragma unroll
            for (int nt = 0; nt < 4; ++nt)
                acc[mt][nt] = __builtin_amdgcn_mfma_f32_16x16x32_bf16(af[mt], bf[nt], acc[mt][nt], 0, 0, 0);
    }

#pragma unroll
    for (int mt = 0; mt < 4; ++mt) {
        int gm_base = m0 + wm * 64 + mt * 16 + lq * 4;
#pragma unroll
        for (int nt = 0; nt < 4; ++nt) {
            int gn = n0 + wn * 64 + nt * 16 + lc;
            float bv = bias[gn];
#pragma unroll
            for (int r = 0; r < 4; ++r) {
                int gm = gm_base + r;
                if (gm >= Mrows) continue;
                float v = acc[mt][nt][r] + bv;
                if (ACT == 1) v = gelu_f(v);
                float* cp = C + (size_t)gm * ldc + gn;
                if (RESID) v += *cp;
                *cp = v;
            }
        }
    }
}

// ---------------- MFMA attention: one block per (graph, head); 4 waves, 16-row q-tiles ----------------
// Q/K read from global fp32 -> bf16 frags; V transposed to LDS bf16; per-wave P tile in LDS bf16.
// Softmax in MFMA C-layout; 1/sum folded into O epilogue. O overwrites dead Q slice.
constexpr int PPITCH = 280;  // bf16 elements per row (560 B: 2-way bank aliasing = free)
__global__ __launch_bounds__(256, 2) void attn_mfma(float* __restrict__ qkvb) {
    __shared__ __bf16 Vt[32][PPITCH];        // Vt[d][key], keys 257..271 zeroed
    __shared__ __bf16 Pb[4][16][PPITCH];     // per-wave unnormalized P, [q-row-in-tile][key]
    int bb = blockIdx.x;
    int b = bb >> 3, h = bb & 7;
    int t = threadIdx.x;
    int w = t >> 6, L = t & 63;
    int c = L & 15, quad = L >> 4;
    const float scale = 0.17677669529663687f;  // 1/sqrt(32)
    const size_t rowstride = 768;
    const float* qb = qkvb + (size_t)(b * SEQ) * rowstride + h * 32;         // Q
    const float* kb = qb + 256;                                               // K
    const float* vb = qb + 512;                                               // V
    float* ob = qkvb + (size_t)(b * SEQ) * rowstride + h * 32;               // O (dead Q slice)

    // stage V^T: Vt[d][key] bf16
    for (int idx = t; idx < 32 * 272; idx += 256) {
        int key = idx >> 5, d = idx & 31;
        float v = (key < SEQ) ? vb[(size_t)key * rowstride + d] : 0.f;
        Vt[d][key] = (__bf16)v;
    }
    __syncthreads();

#pragma unroll 1
    for (int qt = 0; qt < 5; ++qt) {
        int q0 = qt * 64 + w * 16;
        if (q0 > 256) continue;
        int ntiles = (qt == 0 && w == 0) ? 17 : (qt * 4 + w + 1);
        if (ntiles > 17) ntiles = 17;
        int nkc = (ntiles + 1) >> 1;

        // Q fragment: lane holds q-row q0 + c, d = quad*8..+7
        bf16x8 qf;
        {
            int qr = q0 + c; if (qr > 256) qr = 256;
            const float* qp = qb + (size_t)qr * rowstride + quad * 8;
            f32x4 v0 = *(const f32x4*)qp;
            f32x4 v1 = *(const f32x4*)(qp + 4);
            qf[0] = (__bf16)v0.x; qf[1] = (__bf16)v0.y; qf[2] = (__bf16)v0.z; qf[3] = (__bf16)v0.w;
            qf[4] = (__bf16)v1.x; qf[5] = (__bf16)v1.y; qf[6] = (__bf16)v1.z; qf[7] = (__bf16)v1.w;
        }

        // QK^T: one mfma per 16-key tile
        f32x4 acc[17];
#pragma unroll
        for (int tt = 0; tt < 17; ++tt) {
            if (tt >= ntiles) continue;
            int kr = tt * 16 + c; if (kr > 256) kr = 256;
            const float* kp = kb + (size_t)kr * rowstride + quad * 8;
            f32x4 v0 = *(const f32x4*)kp;
            f32x4 v1 = *(const f32x4*)(kp + 4);
            bf16x8 kf;
            kf[0] = (__bf16)v0.x; kf[1] = (__bf16)v0.y; kf[2] = (__bf16)v0.z; kf[3] = (__bf16)v0.w;
            kf[4] = (__bf16)v1.x; kf[5] = (__bf16)v1.y; kf[6] = (__bf16)v1.z; kf[7] = (__bf16)v1.w;
            f32x4 z = {0.f, 0.f, 0.f, 0.f};
            acc[tt] = __builtin_amdgcn_mfma_f32_16x16x32_bf16(qf, kf, z, 0, 0, 0);
        }

        // masked softmax (C-layout: lane holds rows quad*4+j, col c of each tile)
        float inv[4];
#pragma unroll
        for (int j = 0; j < 4; ++j) {
            int q = q0 + quad * 4 + j;
            float mx = -3.0e38f;
#pragma unroll
            for (int tt = 0; tt < 17; ++tt) {
                if (tt >= ntiles) continue;
                int key = tt * 16 + c;
                bool ok = (key < SEQ) && (q == 0 || key <= q);
                float v = ok ? acc[tt][j] * scale : -3.0e38f;
                mx = fmaxf(mx, v);
            }
            mx = fmaxf(mx, __shfl_xor(mx, 1));
            mx = fmaxf(mx, __shfl_xor(mx, 2));
            mx = fmaxf(mx, __shfl_xor(mx, 4));
            mx = fmaxf(mx, __shfl_xor(mx, 8));
            float s = 0.f;
#pragma unroll
            for (int tt = 0; tt < 17; ++tt) {
                if (tt >= ntiles) continue;
                int key = tt * 16 + c;
                bool ok = (key < SEQ) && (q == 0 || key <= q);
                float pv = ok ? expf(acc[tt][j] * scale - mx) : 0.f;
                s += pv;
                Pb[w][quad * 4 + j][key] = (__bf16)pv;
            }
            if ((ntiles & 1) && ntiles < 17)  // zero pad tile so PV's 32-wide reads see zeros
                Pb[w][quad * 4 + j][ntiles * 16 + c] = (__bf16)0.f;
            s += __shfl_xor(s, 1);
            s += __shfl_xor(s, 2);
            s += __shfl_xor(s, 4);
            s += __shfl_xor(s, 8);
            inv[j] = 1.0f / s;
        }

        // PV: O[16][32] = P[16][keys] @ V[keys][32]
        f32x4 oacc0 = {0.f, 0.f, 0.f, 0.f};
        f32x4 oacc1 = {0.f, 0.f, 0.f, 0.f};
#pragma unroll
        for (int kc = 0; kc < 9; ++kc) {
            if (kc >= nkc) continue;
            int off = kc * 32 + quad * 8;
            bf16x8 af = {};
            bf16x8 bf0 = {};
            bf16x8 bf1 = {};
            if (off < 257) {
                af  = *(const bf16x8*)&Pb[w][c][off];
                bf0 = *(const bf16x8*)&Vt[c][off];
                bf1 = *(const bf16x8*)&Vt[16 + c][off];
            }
            oacc0 = __builtin_amdgcn_mfma_f32_16x16x32_bf16(af, bf0, oacc0, 0, 0, 0);
            oacc1 = __builtin_amdgcn_mfma_f32_16x16x32_bf16(af, bf1, oacc1, 0, 0, 0);
        }

        // epilogue: apply 1/sum, write O rows (C-layout rows match inv[] rows)
#pragma unroll
        for (int j = 0; j < 4; ++j) {
            int q = q0 + quad * 4 + j;
            if (q < SEQ) {
                float* op = ob + (size_t)q * rowstride;
                op[c]      = oacc0[j] * inv[j];
                op[16 + c] = oacc1[j] * inv[j];
            }
        }
    }
}

// ---------------- fp32 tiled GEMM (kept for GCN projection) ----------------
template <int ACT, bool RESID, bool REMAP>
__global__ __launch_bounds__(256) void gemm_std(const float* __restrict__ A, int lda,
                                                const float* __restrict__ Bw, int ldb,
                                                const float* __restrict__ bias,
                                                float* __restrict__ C, int ldc, int Ktot) {
    int t = threadIdx.x;
    int m0 = blockIdx.x << 6, n0 = blockIdx.y << 6;
    __shared__ float As[16][68];
    __shared__ float Bs[16][64];
    int arow = t >> 2, akk = (t & 3) << 2;
    int bk = t >> 4, bn = (t & 15) << 2;
    int tm = (t >> 4) << 2, tn = (t & 15) << 2;
    float acc[4][4] = {};
    const float* ap = A + (size_t)(m0 + arow) * lda + akk;
    const float* bp = Bw + (size_t)bk * ldb + n0 + bn;
    for (int k0 = 0; k0 < Ktot; k0 += 16) {
        float4 av = *(const float4*)(ap + k0);
        float4 bv = *(const float4*)(bp + (size_t)k0 * ldb);
        __syncthreads();
        As[akk + 0][arow] = av.x; As[akk + 1][arow] = av.y;
        As[akk + 2][arow] = av.z; As[akk + 3][arow] = av.w;
        *(float4*)&Bs[bk][bn] = bv;
        __syncthreads();
#pragma unroll
        for (int k = 0; k < 16; ++k) {
            float4 a = *(const float4*)&As[k][tm];
            float4 b = *(const float4*)&Bs[k][tn];
            acc[0][0] += a.x * b.x; acc[0][1] += a.x * b.y; acc[0][2] += a.x * b.z; acc[0][3] += a.x * b.w;
            acc[1][0] += a.y * b.x; acc[1][1] += a.y * b.y; acc[1][2] += a.y * b.z; acc[1][3] += a.y * b.w;
            acc[2][0] += a.z * b.x; acc[2][1] += a.z * b.y; acc[2][2] += a.z * b.z; acc[2][3] += a.z * b.w;
            acc[3][0] += a.w * b.x; acc[3][1] += a.w * b.y; acc[3][2] += a.w * b.z; acc[3][3] += a.w * b.w;
        }
    }
#pragma unroll
    for (int i = 0; i < 4; ++i) {
        int gm = m0 + tm + i;
        int orow = REMAP ? (gm + (gm >> 8) + 1) : gm;  // node -> xd row (skip cls slots)
        float* cp = C + (size_t)orow * ldc + n0 + tn;
        float4 r;
        r.x = acc[i][0] + bias[n0 + tn + 0];
        r.y = acc[i][1] + bias[n0 + tn + 1];
        r.z = acc[i][2] + bias[n0 + tn + 2];
        r.w = acc[i][3] + bias[n0 + tn + 3];
        if (ACT == 1) { r.x = gelu_f(r.x); r.y = gelu_f(r.y); r.z = gelu_f(r.z); r.w = gelu_f(r.w); }
        if (ACT == 2) { r.x = fmaxf(r.x, 0.f); r.y = fmaxf(r.y, 0.f); r.z = fmaxf(r.z, 0.f); r.w = fmaxf(r.w, 0.f); }
        if (RESID) {
            float4 o = *(const float4*)cp;
            r.x += o.x; r.y += o.y; r.z += o.z; r.w += o.w;
        }
        *(float4*)cp = r;
    }
}

// ---------------- decoder FC: grid (sample, out-chunk), 4 waves split K ----------------
template <int K, int NOUT>
__global__ __launch_bounds__(256) void dec_fc2(const float* __restrict__ in, const float* __restrict__ w,
                                               const float* __restrict__ bia, float* __restrict__ out) {
    __shared__ float rowbuf[K];
    __shared__ float part[4][64];
    int b = blockIdx.x, c = blockIdx.y, t = threadIdx.x;
    for (int i = t; i < K; i += 256) rowbuf[i] = in[(size_t)b * K + i];
    __syncthreads();
    int lane = t & 63, wv = t >> 6;
    int n = c * 64 + lane;
    const int KQ = K / 4;
    const float* wp = w + (size_t)(wv * KQ) * NOUT + n;
    float s = 0.f;
#pragma unroll 8
    for (int k = 0; k < KQ; ++k) s += rowbuf[wv * KQ + k] * wp[(size_t)k * NOUT];
    part[wv][lane] = s;
    __syncthreads();
    if (wv == 0) {
        float r = part[0][lane] + part[1][lane] + part[2][lane] + part[3][lane] + bia[n];
        out[(size_t)b * NOUT + n] = fmaxf(r, 0.f);
    }
}

// ---------------- launch ----------------
extern "C" void kernel_launch(void* const* d_in, const int* in_sizes, int n_in,
                              void* d_out, int out_size, void* d_ws, size_t ws_size,
                              hipStream_t stream) {
    const float* x         = (const float*)d_in[0];
    const float* p         = (const float*)d_in[1];
    const int*   ei        = (const int*)d_in[2];
    const float* gcn_w     = (const float*)d_in[4];
    const float* gcn_b     = (const float*)d_in[5];
    const float* cls_tok   = (const float*)d_in[6];
    const float* ln_pre_s  = (const float*)d_in[7];
    const float* ln_pre_b  = (const float*)d_in[8];
    const float* norm1_s   = (const float*)d_in[9];
    const float* norm1_b   = (const float*)d_in[10];
    const float* in_proj_w = (const float*)d_in[11];
    const float* in_proj_b = (const float*)d_in[12];
    const float* out_proj_w= (const float*)d_in[13];
    const float* out_proj_b= (const float*)d_in[14];
    const float* norm2_s   = (const float*)d_in[15];
    const float* norm2_b   = (const float*)d_in[16];
    const float* ff_w1     = (const float*)d_in[17];
    const float* ff_b1     = (const float*)d_in[18];
    const float* ff_w2     = (const float*)d_in[19];
    const float* ff_b2     = (const float*)d_in[20];
    const float* ln_post_s = (const float*)d_in[21];
    const float* ln_post_b = (const float*)d_in[22];
    const float* dec_w1    = (const float*)d_in[23];
    const float* dec_b1    = (const float*)d_in[24];
    const float* dec_w2    = (const float*)d_in[25];
    const float* dec_b2    = (const float*)d_in[26];
    const float* dec_w3    = (const float*)d_in[27];
    const float* dec_b3    = (const float*)d_in[28];

    float* ws   = (float*)d_ws;
    float* y    = ws + F_Y;
    float* agg  = ws + F_AGG;
    float* xd   = ws + F_XD;
    float* h1   = ws + F_H1;
    float* qkv  = ws + F_QKV;
    float* ffb  = ws + F_FFB;
    float* cls  = ws + F_CLS;
    float* dd1  = ws + F_D1;
    float* dd2  = ws + F_D2;
    float* wpad = ws + F_WPAD;
    float* dinv = ws + F_DINV;
    int* ibase  = (int*)(ws + F_END);
    int* indeg  = ibase;
    int* offs   = ibase + N_NODES;
    int* cursor = offs + N_NODES + 1;
    int* csr    = cursor + N_NODES;
    __bf16* wtb = (__bf16*)(csr + NEDGE);
    __bf16* wt_in  = wtb;                         // 2 x 768*256
    __bf16* wt_out = wt_in  + 2 * 768 * 256;      // 2 x 256*256
    __bf16* wt_f1  = wt_out + 2 * 256 * 256;      // 2 x 1024*256
    __bf16* wt_f2  = wt_f1  + 2 * 1024 * 256;     // 2 x 256*1024

    // GCN prelude
    hipMemsetAsync(indeg, 0, N_NODES * sizeof(int), stream);
    hist_kernel<<<NEDGE / 256, 256, 0, stream>>>(ei + NEDGE, indeg);
    scan_kernel<<<1, 1024, 0, stream>>>(indeg, offs, cursor, dinv);
    fill_kernel<<<NEDGE / 256, 256, 0, stream>>>(ei, cursor, csr);
    y_kernel<<<N_NODES * 64 / 256, 256, 0, stream>>>(x, p, dinv, y);
    agg_kernel<<<N_NODES / 4, 256, 0, stream>>>(y, dinv, offs, csr, agg);
    wpad_kernel<<<64, 256, 0, stream>>>(gcn_w, wpad);

    // weight transpose+cast (once per call)
    for (int l = 0; l < 2; ++l) {
        tcast_kernel<<<dim3(4, 12), 256, 0, stream>>>(in_proj_w + (size_t)l * 256 * 768,
                                                      wt_in + (size_t)l * 768 * 256, 256, 768);
        tcast_kernel<<<dim3(4, 4), 256, 0, stream>>>(out_proj_w + (size_t)l * 256 * 256,
                                                     wt_out + (size_t)l * 256 * 256, 256, 256);
        tcast_kernel<<<dim3(4, 16), 256, 0, stream>>>(ff_w1 + (size_t)l * 256 * 1024,
                                                      wt_f1 + (size_t)l * 1024 * 256, 256, 1024);
        tcast_kernel<<<dim3(16, 4), 256, 0, stream>>>(ff_w2 + (size_t)l * 1024 * 256,
                                                      wt_f2 + (size_t)l * 256 * 1024, 1024, 256);
    }

    // GCN matmul -> xd rows (remapped past cls slots), fp32
    gemm_std<0, false, true><<<dim3(256, 4), 256, 0, stream>>>(agg, 64, wpad, 256, gcn_b, xd, 256, 64);
    cls_write<<<64, 256, 0, stream>>>(cls_tok, xd);
    ln_kernel<<<MROWS, 256, 0, stream>>>(xd, xd, ln_pre_s, ln_pre_b, 1, 1);

    const int MB = (MROWS + 127) / 128;  // 129
    for (int l = 0; l < 2; ++l) {
        ln_kernel<<<MROWS, 256, 0, stream>>>(xd, h1, norm1_s + l * WDIM, norm1_b + l * WDIM, 1, 1);
        gemm_mfma<0, false><<<dim3(MB, 6), 256, 0, stream>>>(
            h1, 256, wt_in + (size_t)l * 768 * 256, in_proj_b + l * 768, qkv, 768, 256, MROWS);
        attn_mfma<<<512, 256, 0, stream>>>(qkv);
        gemm_mfma<0, true><<<dim3(MB, 2), 256, 0, stream>>>(
            qkv, 768, wt_out + (size_t)l * 256 * 256, out_proj_b + l * WDIM, xd, 256, 256, MROWS);
        ln_kernel<<<MROWS, 256, 0, stream>>>(xd, h1, norm2_s + l * WDIM, norm2_b + l * WDIM, 1, 1);
        gemm_mfma<1, false><<<dim3(MB, 8), 256, 0, stream>>>(
            h1, 256, wt_f1 + (size_t)l * 1024 * 256, ff_b1 + l * DFF, ffb, 1024, 256, MROWS);
        gemm_mfma<1, true><<<dim3(MB, 2), 256, 0, stream>>>(
            ffb, 1024, wt_f2 + (size_t)l * 256 * 1024, ff_b2 + l * WDIM, xd, 256, 1024, MROWS);
    }

    // cls extract + ln_post + decoder
    ln_kernel<<<BGRAPH, 256, 0, stream>>>(xd, cls, ln_post_s, ln_post_b, SEQ, 1);
    dec_fc2<256, 512><<<dim3(BGRAPH, 8), 256, 0, stream>>>(cls, dec_w1, dec_b1, dd1);
    dec_fc2<512, 512><<<dim3(BGRAPH, 8), 256, 0, stream>>>(dd1, dec_w2, dec_b2, dd2);
    dec_fc2<512, 64><<<dim3(BGRAPH, 1), 256, 0, stream>>>(dd2, dec_w3, dec_b3, (float*)d_out);
}

// Round 5
// 786.317 us; speedup vs baseline: 1.9450x; 1.0838x over previous
//
#include <hip/hip_runtime.h>
#include <math.h>

// ---------------- model dims ----------------
constexpr int N_NODES = 16384;
constexpr int BGRAPH  = 64;
constexpr int NEDGE   = 524288;
constexpr int SEQ     = 257;           // NPG + cls
constexpr int WDIM    = 256;
constexpr int DFF     = 1024;
constexpr int HID     = 512;
constexpr int MROWS   = BGRAPH * SEQ;  // 16448

// ---------------- ws layout (float offsets for fp32 region) ----------------
constexpr size_t F_Y    = 0;                                   // [N,64]
constexpr size_t F_AGG  = F_Y    + (size_t)N_NODES * 64;       // [N,64]
constexpr size_t F_XD   = F_AGG  + (size_t)N_NODES * 64;       // [16448,256] residual (fp32)
constexpr size_t F_CLS  = F_XD   + (size_t)MROWS * WDIM;       // [64,256]
constexpr size_t F_D1   = F_CLS  + (size_t)BGRAPH * WDIM;      // [64,512]
constexpr size_t F_D2   = F_D1   + (size_t)BGRAPH * HID;       // [64,512]
constexpr size_t F_WPAD = F_D2   + (size_t)BGRAPH * HID;       // [64,256]
constexpr size_t F_DINV = F_WPAD + (size_t)64 * WDIM;          // [N]
constexpr size_t F_IEND = F_DINV + (size_t)N_NODES;

typedef __attribute__((ext_vector_type(8))) __bf16 bf16x8;
typedef __attribute__((ext_vector_type(4))) __bf16 bf16x4;
typedef __attribute__((ext_vector_type(4))) float f32x4;

__device__ __forceinline__ float gelu_f(float x) {
    float u = 0.7978845608028654f * (x + 0.044715f * x * x * x);
    return 0.5f * x * (1.0f + tanhf(u));
}

// ---------------- GCN prelude ----------------
__global__ __launch_bounds__(256) void hist_kernel(const int* __restrict__ col, int* __restrict__ indeg) {
    int e = blockIdx.x * 256 + threadIdx.x;
    atomicAdd(&indeg[col[e]], 1);
}

__global__ __launch_bounds__(1024) void scan_kernel(const int* __restrict__ indeg, int* __restrict__ offs,
                                                    int* __restrict__ cursor, float* __restrict__ dinv) {
    __shared__ int parts[1024];
    int t = threadIdx.x;
    int base = t * 16;
    int loc[16];
    int s = 0;
#pragma unroll
    for (int i = 0; i < 16; ++i) { loc[i] = indeg[base + i]; s += loc[i]; }
    parts[t] = s;
    __syncthreads();
    for (int off = 1; off < 1024; off <<= 1) {
        int v = (t >= off) ? parts[t - off] : 0;
        __syncthreads();
        parts[t] += v;
        __syncthreads();
    }
    int run = (t == 0) ? 0 : parts[t - 1];
#pragma unroll
    for (int i = 0; i < 16; ++i) {
        offs[base + i] = run;
        cursor[base + i] = run;
        dinv[base + i] = rsqrtf((float)loc[i] + 1.0f);  // deg = indeg + self-loop
        run += loc[i];
    }
    if (t == 1023) offs[N_NODES] = run;
}

__global__ __launch_bounds__(256) void fill_kernel(const int* __restrict__ ei, int* __restrict__ cursor,
                                                   int* __restrict__ csr) {
    int e = blockIdx.x * 256 + threadIdx.x;
    int r = ei[e];            // source
    int c = ei[NEDGE + e];    // destination
    int pos = atomicAdd(&cursor[c], 1);
    csr[pos] = r;
}

// xc = [x(32) | sin(p*2^j*pi)(24) | 0(8)], pre-scaled by dinv[node]
__global__ __launch_bounds__(256) void y_kernel(const float* __restrict__ x, const float* __restrict__ p,
                                                const float* __restrict__ dinv, float* __restrict__ y) {
    int idx = blockIdx.x * 256 + threadIdx.x;
    int i = idx >> 6, d = idx & 63;
    float v = 0.f;
    if (d < 32) {
        v = x[i * 32 + d];
    } else if (d < 56) {
        int dd = d - 32;
        int dim = dd >> 3, j = dd & 7;
        v = sinf(p[i * 3 + dim] * (3.14159265358979323846f * (float)(1 << j)));
    }
    y[idx] = dinv[i] * v;
}

// agg[c] = dinv[c] * (y[c] + sum_{in-edges} y[src])   (wave per node)
__global__ __launch_bounds__(256) void agg_kernel(const float* __restrict__ y, const float* __restrict__ dinv,
                                                  const int* __restrict__ offs, const int* __restrict__ csr,
                                                  float* __restrict__ agg) {
    int c = (blockIdx.x * 256 + threadIdx.x) >> 6;
    int lane = threadIdx.x & 63;
    float acc = y[(size_t)c * 64 + lane];
    int s = offs[c], e = offs[c + 1];
    for (int j = s; j < e; ++j) {
        int r = csr[j];
        acc += y[(size_t)r * 64 + lane];
    }
    agg[(size_t)c * 64 + lane] = dinv[c] * acc;
}

__global__ __launch_bounds__(256) void wpad_kernel(const float* __restrict__ w, float* __restrict__ wp) {
    int idx = blockIdx.x * 256 + threadIdx.x;
    wp[idx] = (idx < 56 * 256) ? w[idx] : 0.f;
}

__global__ __launch_bounds__(256) void cls_write(const float* __restrict__ tok, float* __restrict__ xd) {
    xd[(size_t)blockIdx.x * SEQ * WDIM + threadIdx.x] = tok[threadIdx.x];
}

// ---------------- LayerNorm: wave per row, 4 rows/block, no barriers ----------------
template <int OUTBF>
__global__ __launch_bounds__(256) void ln4_kernel(const float* __restrict__ in, int rin_stride,
                                                  void* __restrict__ out,
                                                  const float* __restrict__ g, const float* __restrict__ be) {
    int w = threadIdx.x >> 6, lane = threadIdx.x & 63;
    int row = blockIdx.x * 4 + w;
    const float* ip = in + (size_t)row * rin_stride + lane * 4;
    f32x4 v = *(const f32x4*)ip;
    float s = v[0] + v[1] + v[2] + v[3];
    float ss = v[0] * v[0] + v[1] * v[1] + v[2] * v[2] + v[3] * v[3];
#pragma unroll
    for (int off = 1; off < 64; off <<= 1) { s += __shfl_xor(s, off); ss += __shfl_xor(ss, off); }
    float mean = s * 0.00390625f;
    float var = ss * 0.00390625f - mean * mean;
    float rs = rsqrtf(var + 1e-5f);
    f32x4 gv = *(const f32x4*)(g + lane * 4);
    f32x4 bv = *(const f32x4*)(be + lane * 4);
    if (OUTBF) {
        bf16x4 o;
#pragma unroll
        for (int i = 0; i < 4; ++i) o[i] = (__bf16)((v[i] - mean) * rs * gv[i] + bv[i]);
        *(bf16x4*)((__bf16*)out + (size_t)row * 256 + lane * 4) = o;
    } else {
        f32x4 o;
#pragma unroll
        for (int i = 0; i < 4; ++i) o[i] = (v[i] - mean) * rs * gv[i] + bv[i];
        *(f32x4*)((float*)out + (size_t)row * 256 + lane * 4) = o;
    }
}

// ---------------- weight transpose+cast: W[K][N] fp32 -> Wt[N][K] bf16 ----------------
__global__ __launch_bounds__(256) void tcast_kernel(const float* __restrict__ W, __bf16* __restrict__ Wt,
                                                    int K, int N) {
    __shared__ __bf16 T[64][65];
    int t = threadIdx.x;
    int k0 = blockIdx.x << 6, n0 = blockIdx.y << 6;
#pragma unroll
    for (int i = 0; i < 16; ++i) {
        int idx = t + i * 256;
        int k = idx >> 6, n = idx & 63;
        T[k][n] = (__bf16)W[(size_t)(k0 + k) * N + n0 + n];
    }
    __syncthreads();
#pragma unroll
    for (int i = 0; i < 16; ++i) {
        int idx = t + i * 256;
        int n = idx >> 6, k = idx & 63;
        Wt[(size_t)(n0 + n) * K + k0 + k] = T[k][n];
    }
}

// ---------------- bf16 MFMA GEMM: C[M,N] = epi(A[M,K](bf16) @ Bt[N,K](bf16) + bias) ----------------
// BM=128, BN in {128,64}. 4 waves: wm=w>>1 (64 rows), wn=w&1 (BN/2 cols).
// LDS pitch 36 (72 B rows) -> near-conflict-free ds_read_b128 / ds_write.
// OMODE 0: bf16 store (no resid). OMODE 1: fp32 store += resid.
constexpr int LP = 36;
template <int BN, int ACT, int OMODE>
__global__ __launch_bounds__(256) void gemm_bf(const __bf16* __restrict__ A, int lda,
                                               const __bf16* __restrict__ Bt,
                                               const float* __restrict__ bias,
                                               void* __restrict__ Cv, int ldc,
                                               int Ktot, int Mrows) {
    constexpr int NTW = BN / 32;  // n-tiles per wave
    __shared__ __bf16 As[128 * LP];
    __shared__ __bf16 Bs[BN * LP];
    int t = threadIdx.x;
    int m0 = blockIdx.x << 7, n0 = blockIdx.y * BN;
    int w = t >> 6, L = t & 63;
    int wm = w >> 1, wn = w & 1;
    int lc = L & 15, quad = L >> 4;

    // A staging: thread t -> row t>>1, 16-elem chunk (t&1)*16 (+8 for second bf16x8)
    int sa_row = t >> 1, sa_off = (t & 1) << 4;
    const __bf16* ap = A + (size_t)(m0 + sa_row) * lda + sa_off;
    __bf16* as_dst = &As[sa_row * LP + sa_off];
    const __bf16* bp;
    __bf16* bs_dst;
    if constexpr (BN == 128) {
        bp = Bt + (size_t)(n0 + sa_row) * Ktot + sa_off;
        bs_dst = &Bs[sa_row * LP + sa_off];
    } else {
        int sb_row = t >> 2, sb_off = (t & 3) << 3;
        bp = Bt + (size_t)(n0 + sb_row) * Ktot + sb_off;
        bs_dst = &Bs[sb_row * LP + sb_off];
    }

    int a_base = (wm * 64 + lc) * LP + quad * 8;
    int b_base = (wn * (BN / 2) + lc) * LP + quad * 8;

    f32x4 acc[4][NTW] = {};

    for (int k0 = 0; k0 < Ktot; k0 += 32) {
        bf16x8 a0 = *(const bf16x8*)(ap + k0);
        bf16x8 a1 = *(const bf16x8*)(ap + k0 + 8);
        bf16x8 b0, b1;
        if constexpr (BN == 128) {
            b0 = *(const bf16x8*)(bp + k0);
            b1 = *(const bf16x8*)(bp + k0 + 8);
        } else {
            b0 = *(const bf16x8*)(bp + k0);
        }
        __syncthreads();
        *(bf16x8*)as_dst = a0;
        *(bf16x8*)(as_dst + 8) = a1;
        if constexpr (BN == 128) {
            *(bf16x8*)bs_dst = b0;
            *(bf16x8*)(bs_dst + 8) = b1;
        } else {
            *(bf16x8*)bs_dst = b0;
        }
        __syncthreads();
        bf16x8 af[4], bfr[NTW];
#pragma unroll
        for (int i = 0; i < 4; ++i) af[i] = *(const bf16x8*)&As[a_base + i * 16 * LP];
#pragma unroll
        for (int i = 0; i < NTW; ++i) bfr[i] = *(const bf16x8*)&Bs[b_base + i * 16 * LP];
#pragma unroll
        for (int mt = 0; mt < 4; ++mt)
#pragma unroll
            for (int nt = 0; nt < NTW; ++nt)
                acc[mt][nt] = __builtin_amdgcn_mfma_f32_16x16x32_bf16(af[mt], bfr[nt], acc[mt][nt], 0, 0, 0);
    }

#pragma unroll
    for (int mt = 0; mt < 4; ++mt) {
        int gmb = m0 + wm * 64 + mt * 16 + quad * 4;
#pragma unroll
        for (int nt = 0; nt < NTW; ++nt) {
            int gn = n0 + wn * (BN / 2) + nt * 16 + lc;
            float bv = bias[gn];
#pragma unroll
            for (int r = 0; r < 4; ++r) {
                int gm = gmb + r;
                if (gm >= Mrows) continue;
                float v = acc[mt][nt][r] + bv;
                if (ACT == 1) v = gelu_f(v);
                if (OMODE == 0) {
                    ((__bf16*)Cv)[(size_t)gm * ldc + gn] = (__bf16)v;
                } else {
                    float* cp = (float*)Cv + (size_t)gm * ldc + gn;
                    *cp = v + *cp;
                }
            }
        }
    }
}

// ---------------- MFMA attention on bf16 qkv; O -> compact bf16 buffer ----------------
constexpr int PPITCH = 280;
__global__ __launch_bounds__(256, 2) void attn_mfma(const __bf16* __restrict__ qkvb,
                                                    __bf16* __restrict__ obuf) {
    __shared__ __bf16 Vt[32][PPITCH];        // Vt[d][key], keys 257..271 zeroed
    __shared__ __bf16 Pb[4][16][PPITCH];     // per-wave unnormalized P
    int bb = blockIdx.x;
    int b = bb >> 3, h = bb & 7;
    int t = threadIdx.x;
    int w = t >> 6, L = t & 63;
    int c = L & 15, quad = L >> 4;
    const float scale = 0.17677669529663687f;  // 1/sqrt(32)
    const __bf16* qb = qkvb + (size_t)(b * SEQ) * 768 + h * 32;
    const __bf16* kb = qb + 256;
    const __bf16* vb = qb + 512;
    __bf16* ob = obuf + (size_t)(b * SEQ) * 256 + h * 32;

    // stage V^T (vector load, scalar transpose-store)
    for (int idx = t; idx < 272 * 4; idx += 256) {
        int key = idx >> 2, dc = (idx & 3) * 8;
        bf16x8 vv = {};
        if (key < SEQ) vv = *(const bf16x8*)(vb + (size_t)key * 768 + dc);
#pragma unroll
        for (int j = 0; j < 8; ++j) Vt[dc + j][key] = vv[j];
    }
    __syncthreads();

#pragma unroll 1
    for (int qt = 0; qt < 5; ++qt) {
        int q0 = qt * 64 + w * 16;
        if (q0 > 256) continue;
        int ntiles = (qt == 0 && w == 0) ? 17 : (qt * 4 + w + 1);
        if (ntiles > 17) ntiles = 17;
        int nkc = (ntiles + 1) >> 1;

        // Q fragment
        bf16x8 qf;
        {
            int qr = q0 + c; if (qr > 256) qr = 256;
            qf = *(const bf16x8*)(qb + (size_t)qr * 768 + quad * 8);
        }

        // QK^T
        f32x4 acc[17];
#pragma unroll
        for (int tt = 0; tt < 17; ++tt) {
            if (tt >= ntiles) continue;
            int kr = tt * 16 + c; if (kr > 256) kr = 256;
            bf16x8 kf = *(const bf16x8*)(kb + (size_t)kr * 768 + quad * 8);
            f32x4 z = {0.f, 0.f, 0.f, 0.f};
            acc[tt] = __builtin_amdgcn_mfma_f32_16x16x32_bf16(qf, kf, z, 0, 0, 0);
        }

        // masked softmax in C-layout
        float inv[4];
#pragma unroll
        for (int j = 0; j < 4; ++j) {
            int q = q0 + quad * 4 + j;
            float mx = -3.0e38f;
#pragma unroll
            for (int tt = 0; tt < 17; ++tt) {
                if (tt >= ntiles) continue;
                int key = tt * 16 + c;
                bool ok = (key < SEQ) && (q == 0 || key <= q);
                float v = ok ? acc[tt][j] * scale : -3.0e38f;
                mx = fmaxf(mx, v);
            }
            mx = fmaxf(mx, __shfl_xor(mx, 1));
            mx = fmaxf(mx, __shfl_xor(mx, 2));
            mx = fmaxf(mx, __shfl_xor(mx, 4));
            mx = fmaxf(mx, __shfl_xor(mx, 8));
            float s = 0.f;
#pragma unroll
            for (int tt = 0; tt < 17; ++tt) {
                if (tt >= ntiles) continue;
                int key = tt * 16 + c;
                bool ok = (key < SEQ) && (q == 0 || key <= q);
                float pv = ok ? expf(acc[tt][j] * scale - mx) : 0.f;
                s += pv;
                Pb[w][quad * 4 + j][key] = (__bf16)pv;
            }
            if ((ntiles & 1) && ntiles < 17)
                Pb[w][quad * 4 + j][ntiles * 16 + c] = (__bf16)0.f;
            s += __shfl_xor(s, 1);
            s += __shfl_xor(s, 2);
            s += __shfl_xor(s, 4);
            s += __shfl_xor(s, 8);
            inv[j] = 1.0f / s;
        }

        // PV
        f32x4 oacc0 = {0.f, 0.f, 0.f, 0.f};
        f32x4 oacc1 = {0.f, 0.f, 0.f, 0.f};
#pragma unroll
        for (int kc = 0; kc < 9; ++kc) {
            if (kc >= nkc) continue;
            int off = kc * 32 + quad * 8;
            bf16x8 af = {};
            bf16x8 bf0 = {};
            bf16x8 bf1 = {};
            if (off < 257) {
                af  = *(const bf16x8*)&Pb[w][c][off];
                bf0 = *(const bf16x8*)&Vt[c][off];
                bf1 = *(const bf16x8*)&Vt[16 + c][off];
            }
            oacc0 = __builtin_amdgcn_mfma_f32_16x16x32_bf16(af, bf0, oacc0, 0, 0, 0);
            oacc1 = __builtin_amdgcn_mfma_f32_16x16x32_bf16(af, bf1, oacc1, 0, 0, 0);
        }

        // epilogue: apply 1/sum, write bf16 O
#pragma unroll
        for (int j = 0; j < 4; ++j) {
            int q = q0 + quad * 4 + j;
            if (q < SEQ) {
                __bf16* op = ob + (size_t)q * 256;
                op[c]      = (__bf16)(oacc0[j] * inv[j]);
                op[16 + c] = (__bf16)(oacc1[j] * inv[j]);
            }
        }
    }
}

// ---------------- fp32 tiled GEMM (kept for GCN projection) ----------------
template <int ACT, bool RESID, bool REMAP>
__global__ __launch_bounds__(256) void gemm_std(const float* __restrict__ A, int lda,
                                                const float* __restrict__ Bw, int ldb,
                                                const float* __restrict__ bias,
                                                float* __restrict__ C, int ldc, int Ktot) {
    int t = threadIdx.x;
    int m0 = blockIdx.x << 6, n0 = blockIdx.y << 6;
    __shared__ float As[16][68];
    __shared__ float Bs[16][64];
    int arow = t >> 2, akk = (t & 3) << 2;
    int bk = t >> 4, bn = (t & 15) << 2;
    int tm = (t >> 4) << 2, tn = (t & 15) << 2;
    float acc[4][4] = {};
    const float* ap = A + (size_t)(m0 + arow) * lda + akk;
    const float* bp = Bw + (size_t)bk * ldb + n0 + bn;
    for (int k0 = 0; k0 < Ktot; k0 += 16) {
        float4 av = *(const float4*)(ap + k0);
        float4 bv = *(const float4*)(bp + (size_t)k0 * ldb);
        __syncthreads();
        As[akk + 0][arow] = av.x; As[akk + 1][arow] = av.y;
        As[akk + 2][arow] = av.z; As[akk + 3][arow] = av.w;
        *(float4*)&Bs[bk][bn] = bv;
        __syncthreads();
#pragma unroll
        for (int k = 0; k < 16; ++k) {
            float4 a = *(const float4*)&As[k][tm];
            float4 b = *(const float4*)&Bs[k][tn];
            acc[0][0] += a.x * b.x; acc[0][1] += a.x * b.y; acc[0][2] += a.x * b.z; acc[0][3] += a.x * b.w;
            acc[1][0] += a.y * b.x; acc[1][1] += a.y * b.y; acc[1][2] += a.y * b.z; acc[1][3] += a.y * b.w;
            acc[2][0] += a.z * b.x; acc[2][1] += a.z * b.y; acc[2][2] += a.z * b.z; acc[2][3] += a.z * b.w;
            acc[3][0] += a.w * b.x; acc[3][1] += a.w * b.y; acc[3][2] += a.w * b.z; acc[3][3] += a.w * b.w;
        }
    }
#pragma unroll
    for (int i = 0; i < 4; ++i) {
        int gm = m0 + tm + i;
        int orow = REMAP ? (gm + (gm >> 8) + 1) : gm;  // node -> xd row (skip cls slots)
        float* cp = C + (size_t)orow * ldc + n0 + tn;
        float4 r;
        r.x = acc[i][0] + bias[n0 + tn + 0];
        r.y = acc[i][1] + bias[n0 + tn + 1];
        r.z = acc[i][2] + bias[n0 + tn + 2];
        r.w = acc[i][3] + bias[n0 + tn + 3];
        if (ACT == 1) { r.x = gelu_f(r.x); r.y = gelu_f(r.y); r.z = gelu_f(r.z); r.w = gelu_f(r.w); }
        if (ACT == 2) { r.x = fmaxf(r.x, 0.f); r.y = fmaxf(r.y, 0.f); r.z = fmaxf(r.z, 0.f); r.w = fmaxf(r.w, 0.f); }
        if (RESID) {
            float4 o = *(const float4*)cp;
            r.x += o.x; r.y += o.y; r.z += o.z; r.w += o.w;
        }
        *(float4*)cp = r;
    }
}

// ---------------- decoder FC: grid (sample, out-chunk), 4 waves split K ----------------
template <int K, int NOUT>
__global__ __launch_bounds__(256) void dec_fc2(const float* __restrict__ in, const float* __restrict__ w,
                                               const float* __restrict__ bia, float* __restrict__ out) {
    __shared__ float rowbuf[K];
    __shared__ float part[4][64];
    int b = blockIdx.x, c = blockIdx.y, t = threadIdx.x;
    for (int i = t; i < K; i += 256) rowbuf[i] = in[(size_t)b * K + i];
    __syncthreads();
    int lane = t & 63, wv = t >> 6;
    int n = c * 64 + lane;
    const int KQ = K / 4;
    const float* wp = w + (size_t)(wv * KQ) * NOUT + n;
    float s = 0.f;
#pragma unroll 8
    for (int k = 0; k < KQ; ++k) s += rowbuf[wv * KQ + k] * wp[(size_t)k * NOUT];
    part[wv][lane] = s;
    __syncthreads();
    if (wv == 0) {
        float r = part[0][lane] + part[1][lane] + part[2][lane] + part[3][lane] + bia[n];
        out[(size_t)b * NOUT + n] = fmaxf(r, 0.f);
    }
}

// ---------------- launch ----------------
extern "C" void kernel_launch(void* const* d_in, const int* in_sizes, int n_in,
                              void* d_out, int out_size, void* d_ws, size_t ws_size,
                              hipStream_t stream) {
    const float* x         = (const float*)d_in[0];
    const float* p         = (const float*)d_in[1];
    const int*   ei        = (const int*)d_in[2];
    const float* gcn_w     = (const float*)d_in[4];
    const float* gcn_b     = (const float*)d_in[5];
    const float* cls_tok   = (const float*)d_in[6];
    const float* ln_pre_s  = (const float*)d_in[7];
    const float* ln_pre_b  = (const float*)d_in[8];
    const float* norm1_s   = (const float*)d_in[9];
    const float* norm1_b   = (const float*)d_in[10];
    const float* in_proj_w = (const float*)d_in[11];
    const float* in_proj_b = (const float*)d_in[12];
    const float* out_proj_w= (const float*)d_in[13];
    const float* out_proj_b= (const float*)d_in[14];
    const float* norm2_s   = (const float*)d_in[15];
    const float* norm2_b   = (const float*)d_in[16];
    const float* ff_w1     = (const float*)d_in[17];
    const float* ff_b1     = (const float*)d_in[18];
    const float* ff_w2     = (const float*)d_in[19];
    const float* ff_b2     = (const float*)d_in[20];
    const float* ln_post_s = (const float*)d_in[21];
    const float* ln_post_b = (const float*)d_in[22];
    const float* dec_w1    = (const float*)d_in[23];
    const float* dec_b1    = (const float*)d_in[24];
    const float* dec_w2    = (const float*)d_in[25];
    const float* dec_b2    = (const float*)d_in[26];
    const float* dec_w3    = (const float*)d_in[27];
    const float* dec_b3    = (const float*)d_in[28];

    float* ws   = (float*)d_ws;
    float* y    = ws + F_Y;
    float* agg  = ws + F_AGG;
    float* xd   = ws + F_XD;
    float* cls  = ws + F_CLS;
    float* dd1  = ws + F_D1;
    float* dd2  = ws + F_D2;
    float* wpad = ws + F_WPAD;
    float* dinv = ws + F_DINV;
    int* ibase  = (int*)(ws + F_IEND);
    int* indeg  = ibase;
    int* offs   = ibase + N_NODES;
    int* cursor = offs + N_NODES + 1;
    int* csr    = cursor + N_NODES;
    uintptr_t ub = ((uintptr_t)(csr + NEDGE) + 15) & ~(uintptr_t)15;
    __bf16* h1b  = (__bf16*)ub;                          // [MROWS,256] (also attention O)
    __bf16* qkvb = h1b  + (size_t)MROWS * 256;           // [MROWS,768]
    __bf16* ffbb = qkvb + (size_t)MROWS * 768;           // [MROWS,1024]
    __bf16* wt_in  = ffbb  + (size_t)MROWS * 1024;       // 2 x 768*256
    __bf16* wt_out = wt_in  + 2 * 768 * 256;             // 2 x 256*256
    __bf16* wt_f1  = wt_out + 2 * 256 * 256;             // 2 x 1024*256
    __bf16* wt_f2  = wt_f1  + 2 * 1024 * 256;            // 2 x 256*1024

    // GCN prelude
    hipMemsetAsync(indeg, 0, N_NODES * sizeof(int), stream);
    hist_kernel<<<NEDGE / 256, 256, 0, stream>>>(ei + NEDGE, indeg);
    scan_kernel<<<1, 1024, 0, stream>>>(indeg, offs, cursor, dinv);
    fill_kernel<<<NEDGE / 256, 256, 0, stream>>>(ei, cursor, csr);
    y_kernel<<<N_NODES * 64 / 256, 256, 0, stream>>>(x, p, dinv, y);
    agg_kernel<<<N_NODES / 4, 256, 0, stream>>>(y, dinv, offs, csr, agg);
    wpad_kernel<<<64, 256, 0, stream>>>(gcn_w, wpad);

    // weight transpose+cast (once per call)
    for (int l = 0; l < 2; ++l) {
        tcast_kernel<<<dim3(4, 12), 256, 0, stream>>>(in_proj_w + (size_t)l * 256 * 768,
                                                      wt_in + (size_t)l * 768 * 256, 256, 768);
        tcast_kernel<<<dim3(4, 4), 256, 0, stream>>>(out_proj_w + (size_t)l * 256 * 256,
                                                     wt_out + (size_t)l * 256 * 256, 256, 256);
        tcast_kernel<<<dim3(4, 16), 256, 0, stream>>>(ff_w1 + (size_t)l * 256 * 1024,
                                                      wt_f1 + (size_t)l * 1024 * 256, 256, 1024);
        tcast_kernel<<<dim3(16, 4), 256, 0, stream>>>(ff_w2 + (size_t)l * 1024 * 256,
                                                      wt_f2 + (size_t)l * 256 * 1024, 1024, 256);
    }

    // GCN matmul -> xd rows (remapped past cls slots), fp32
    gemm_std<0, false, true><<<dim3(256, 4), 256, 0, stream>>>(agg, 64, wpad, 256, gcn_b, xd, 256, 64);
    cls_write<<<64, 256, 0, stream>>>(cls_tok, xd);
    ln4_kernel<0><<<MROWS / 4, 256, 0, stream>>>(xd, 256, xd, ln_pre_s, ln_pre_b);

    const int MB = (MROWS + 127) / 128;  // 129
    for (int l = 0; l < 2; ++l) {
        ln4_kernel<1><<<MROWS / 4, 256, 0, stream>>>(xd, 256, h1b, norm1_s + l * WDIM, norm1_b + l * WDIM);
        gemm_bf<128, 0, 0><<<dim3(MB, 6), 256, 0, stream>>>(
            h1b, 256, wt_in + (size_t)l * 768 * 256, in_proj_b + l * 768, qkvb, 768, 256, MROWS);
        attn_mfma<<<512, 256, 0, stream>>>(qkvb, h1b);
        gemm_bf<64, 0, 1><<<dim3(MB, 4), 256, 0, stream>>>(
            h1b, 256, wt_out + (size_t)l * 256 * 256, out_proj_b + l * WDIM, xd, 256, 256, MROWS);
        ln4_kernel<1><<<MROWS / 4, 256, 0, stream>>>(xd, 256, h1b, norm2_s + l * WDIM, norm2_b + l * WDIM);
        gemm_bf<128, 1, 0><<<dim3(MB, 8), 256, 0, stream>>>(
            h1b, 256, wt_f1 + (size_t)l * 1024 * 256, ff_b1 + l * DFF, ffbb, 1024, 256, MROWS);
        gemm_bf<64, 1, 1><<<dim3(MB, 4), 256, 0, stream>>>(
            ffbb, 1024, wt_f2 + (size_t)l * 256 * 1024, ff_b2 + l * WDIM, xd, 256, 1024, MROWS);
    }

    // cls extract + ln_post + decoder
    ln4_kernel<0><<<BGRAPH / 4, 256, 0, stream>>>(xd, SEQ * WDIM, cls, ln_post_s, ln_post_b);
    dec_fc2<256, 512><<<dim3(BGRAPH, 8), 256, 0, stream>>>(cls, dec_w1, dec_b1, dd1);
    dec_fc2<512, 512><<<dim3(BGRAPH, 8), 256, 0, stream>>>(dd1, dec_w2, dec_b2, dd2);
    dec_fc2<512, 64><<<dim3(BGRAPH, 1), 256, 0, stream>>>(dd2, dec_w3, dec_b3, (float*)d_out);
}

// Round 6
// 741.544 us; speedup vs baseline: 2.0624x; 1.0604x over previous
//
#include <hip/hip_runtime.h>
#include <math.h>

// ---------------- model dims ----------------
constexpr int N_NODES = 16384;
constexpr int BGRAPH  = 64;
constexpr int NEDGE   = 524288;
constexpr int SEQ     = 257;           // NPG + cls
constexpr int WDIM    = 256;
constexpr int DFF     = 1024;
constexpr int HID     = 512;
constexpr int MROWS   = BGRAPH * SEQ;  // 16448

// ---------------- ws layout (float offsets for fp32 region) ----------------
constexpr size_t F_Y    = 0;                                   // [N,64]
constexpr size_t F_AGG  = F_Y    + (size_t)N_NODES * 64;       // [N,64]
constexpr size_t F_XD   = F_AGG  + (size_t)N_NODES * 64;       // [16448,256] residual (fp32)
constexpr size_t F_CLS  = F_XD   + (size_t)MROWS * WDIM;       // [64,256]
constexpr size_t F_D1   = F_CLS  + (size_t)BGRAPH * WDIM;      // [64,512]
constexpr size_t F_D2   = F_D1   + (size_t)BGRAPH * HID;       // [64,512]
constexpr size_t F_WPAD = F_D2   + (size_t)BGRAPH * HID;       // [64,256]
constexpr size_t F_DINV = F_WPAD + (size_t)64 * WDIM;          // [N]
constexpr size_t F_IEND = F_DINV + (size_t)N_NODES;

typedef __attribute__((ext_vector_type(8))) __bf16 bf16x8;
typedef __attribute__((ext_vector_type(4))) __bf16 bf16x4;
typedef __attribute__((ext_vector_type(4))) float f32x4;

__device__ __forceinline__ float gelu_f(float x) {
    float u = 0.7978845608028654f * (x + 0.044715f * x * x * x);
    return 0.5f * x * (1.0f + tanhf(u));
}

// ---------------- GCN prelude ----------------
__global__ __launch_bounds__(256) void hist_kernel(const int* __restrict__ col, int* __restrict__ indeg) {
    int e = blockIdx.x * 256 + threadIdx.x;
    atomicAdd(&indeg[col[e]], 1);
}

__global__ __launch_bounds__(1024) void scan_kernel(const int* __restrict__ indeg, int* __restrict__ offs,
                                                    int* __restrict__ cursor, float* __restrict__ dinv) {
    __shared__ int parts[1024];
    int t = threadIdx.x;
    int base = t * 16;
    int loc[16];
    int s = 0;
#pragma unroll
    for (int i = 0; i < 16; ++i) { loc[i] = indeg[base + i]; s += loc[i]; }
    parts[t] = s;
    __syncthreads();
    for (int off = 1; off < 1024; off <<= 1) {
        int v = (t >= off) ? parts[t - off] : 0;
        __syncthreads();
        parts[t] += v;
        __syncthreads();
    }
    int run = (t == 0) ? 0 : parts[t - 1];
#pragma unroll
    for (int i = 0; i < 16; ++i) {
        offs[base + i] = run;
        cursor[base + i] = run;
        dinv[base + i] = rsqrtf((float)loc[i] + 1.0f);  // deg = indeg + self-loop
        run += loc[i];
    }
    if (t == 1023) offs[N_NODES] = run;
}

__global__ __launch_bounds__(256) void fill_kernel(const int* __restrict__ ei, int* __restrict__ cursor,
                                                   int* __restrict__ csr) {
    int e = blockIdx.x * 256 + threadIdx.x;
    int r = ei[e];            // source
    int c = ei[NEDGE + e];    // destination
    int pos = atomicAdd(&cursor[c], 1);
    csr[pos] = r;
}

// xc = [x(32) | sin(p*2^j*pi)(24) | 0(8)], pre-scaled by dinv[node]
__global__ __launch_bounds__(256) void y_kernel(const float* __restrict__ x, const float* __restrict__ p,
                                                const float* __restrict__ dinv, float* __restrict__ y) {
    int idx = blockIdx.x * 256 + threadIdx.x;
    int i = idx >> 6, d = idx & 63;
    float v = 0.f;
    if (d < 32) {
        v = x[i * 32 + d];
    } else if (d < 56) {
        int dd = d - 32;
        int dim = dd >> 3, j = dd & 7;
        v = sinf(p[i * 3 + dim] * (3.14159265358979323846f * (float)(1 << j)));
    }
    y[idx] = dinv[i] * v;
}

// agg[c] = dinv[c] * (y[c] + sum_{in-edges} y[src])   (wave per node)
__global__ __launch_bounds__(256) void agg_kernel(const float* __restrict__ y, const float* __restrict__ dinv,
                                                  const int* __restrict__ offs, const int* __restrict__ csr,
                                                  float* __restrict__ agg) {
    int c = (blockIdx.x * 256 + threadIdx.x) >> 6;
    int lane = threadIdx.x & 63;
    float acc = y[(size_t)c * 64 + lane];
    int s = offs[c], e = offs[c + 1];
    for (int j = s; j < e; ++j) {
        int r = csr[j];
        acc += y[(size_t)r * 64 + lane];
    }
    agg[(size_t)c * 64 + lane] = dinv[c] * acc;
}

__global__ __launch_bounds__(256) void wpad_kernel(const float* __restrict__ w, float* __restrict__ wp) {
    int idx = blockIdx.x * 256 + threadIdx.x;
    wp[idx] = (idx < 56 * 256) ? w[idx] : 0.f;
}

__global__ __launch_bounds__(256) void cls_write(const float* __restrict__ tok, float* __restrict__ xd) {
    xd[(size_t)blockIdx.x * SEQ * WDIM + threadIdx.x] = tok[threadIdx.x];
}

// ---------------- LayerNorm: wave per row, 4 rows/block, no barriers ----------------
template <int OUTBF>
__global__ __launch_bounds__(256) void ln4_kernel(const float* __restrict__ in, int rin_stride,
                                                  void* __restrict__ out,
                                                  const float* __restrict__ g, const float* __restrict__ be) {
    int w = threadIdx.x >> 6, lane = threadIdx.x & 63;
    int row = blockIdx.x * 4 + w;
    const float* ip = in + (size_t)row * rin_stride + lane * 4;
    f32x4 v = *(const f32x4*)ip;
    float s = v[0] + v[1] + v[2] + v[3];
    float ss = v[0] * v[0] + v[1] * v[1] + v[2] * v[2] + v[3] * v[3];
#pragma unroll
    for (int off = 1; off < 64; off <<= 1) { s += __shfl_xor(s, off); ss += __shfl_xor(ss, off); }
    float mean = s * 0.00390625f;
    float var = ss * 0.00390625f - mean * mean;
    float rs = rsqrtf(var + 1e-5f);
    f32x4 gv = *(const f32x4*)(g + lane * 4);
    f32x4 bv = *(const f32x4*)(be + lane * 4);
    if (OUTBF) {
        bf16x4 o;
#pragma unroll
        for (int i = 0; i < 4; ++i) o[i] = (__bf16)((v[i] - mean) * rs * gv[i] + bv[i]);
        *(bf16x4*)((__bf16*)out + (size_t)row * 256 + lane * 4) = o;
    } else {
        f32x4 o;
#pragma unroll
        for (int i = 0; i < 4; ++i) o[i] = (v[i] - mean) * rs * gv[i] + bv[i];
        *(f32x4*)((float*)out + (size_t)row * 256 + lane * 4) = o;
    }
}

// ---------------- weight transpose+cast: W[K][N] fp32 -> Wt[N][K] bf16 ----------------
__global__ __launch_bounds__(256) void tcast_kernel(const float* __restrict__ W, __bf16* __restrict__ Wt,
                                                    int K, int N) {
    __shared__ __bf16 T[64][65];
    int t = threadIdx.x;
    int k0 = blockIdx.x << 6, n0 = blockIdx.y << 6;
#pragma unroll
    for (int i = 0; i < 16; ++i) {
        int idx = t + i * 256;
        int k = idx >> 6, n = idx & 63;
        T[k][n] = (__bf16)W[(size_t)(k0 + k) * N + n0 + n];
    }
    __syncthreads();
#pragma unroll
    for (int i = 0; i < 16; ++i) {
        int idx = t + i * 256;
        int n = idx >> 6, k = idx & 63;
        Wt[(size_t)(n0 + n) * K + k0 + k] = T[k][n];
    }
}

// ---------------- bf16 MFMA GEMM: C[M,N] = epi(A[M,K](bf16) @ Bt[N,K](bf16) + bias) ----------------
// BM=128, BN in {128,64}. 4 waves: wm=w>>1 (64 rows), wn=w&1 (BN/2 cols).
// LDS pitch 36 -> conflict-free ds ops (SQ_LDS_BANK_CONFLICT = 0 measured r5).
// Register-prefetch pipeline: k+1 tile loads issued right after LDS publish, so
// global latency overlaps the MFMA block; vmcnt wait lands at next LDS store.
// 1D grid, XCD-colocating swizzle: all y-blocks of one m-tile share blockIdx%8
// so A-rows are fetched into ONE XCD L2 instead of NY of them.
// OMODE 0: bf16 store (no resid). OMODE 1: fp32 store += resid.
constexpr int LP = 36;
template <int BN, int ACT, int OMODE>
__global__ __launch_bounds__(256) void gemm_bf(const __bf16* __restrict__ A, int lda,
                                               const __bf16* __restrict__ Bt,
                                               const float* __restrict__ bias,
                                               void* __restrict__ Cv, int ldc,
                                               int Ktot, int Mrows, int MBlocks, int NY) {
    constexpr int NTW = BN / 32;  // n-tiles per wave
    __shared__ __bf16 As[128 * LP];
    __shared__ __bf16 Bs[BN * LP];
    // swizzle decode: f = (m%8) + 8*(y + NY*(m/8))
    int f = blockIdx.x;
    int m8 = f & 7;
    int rest = f >> 3;
    int mg = rest / NY;
    int yb = rest - mg * NY;
    int mb = mg * 8 + m8;
    if (mb >= MBlocks) return;
    int m0 = mb << 7, n0 = yb * BN;

    int t = threadIdx.x;
    int w = t >> 6, L = t & 63;
    int wm = w >> 1, wn = w & 1;
    int lc = L & 15, quad = L >> 4;

    // A staging: thread t -> row t>>1, 16-elem chunk (t&1)*16
    int sa_row = t >> 1, sa_off = (t & 1) << 4;
    const __bf16* ap = A + (size_t)(m0 + sa_row) * lda + sa_off;
    __bf16* as_dst = &As[sa_row * LP + sa_off];
    const __bf16* bp;
    __bf16* bs_dst;
    if constexpr (BN == 128) {
        bp = Bt + (size_t)(n0 + sa_row) * Ktot + sa_off;
        bs_dst = &Bs[sa_row * LP + sa_off];
    } else {
        int sb_row = t >> 2, sb_off = (t & 3) << 3;
        bp = Bt + (size_t)(n0 + sb_row) * Ktot + sb_off;
        bs_dst = &Bs[sb_row * LP + sb_off];
    }

    int a_base = (wm * 64 + lc) * LP + quad * 8;
    int b_base = (wn * (BN / 2) + lc) * LP + quad * 8;

    f32x4 acc[4][NTW] = {};

    // prologue: preload k=0 tile into regs
    bf16x8 a0 = *(const bf16x8*)(ap);
    bf16x8 a1 = *(const bf16x8*)(ap + 8);
    bf16x8 b0, b1;
    if constexpr (BN == 128) {
        b0 = *(const bf16x8*)(bp);
        b1 = *(const bf16x8*)(bp + 8);
    } else {
        b0 = *(const bf16x8*)(bp);
    }

    for (int k0 = 0; k0 < Ktot; k0 += 32) {
        __syncthreads();   // all waves done reading LDS of previous step
        *(bf16x8*)as_dst = a0;            // waits vmcnt for the prefetched regs
        *(bf16x8*)(as_dst + 8) = a1;
        if constexpr (BN == 128) {
            *(bf16x8*)bs_dst = b0;
            *(bf16x8*)(bs_dst + 8) = b1;
        } else {
            *(bf16x8*)bs_dst = b0;
        }
        __syncthreads();   // LDS visible
        if (k0 + 32 < Ktot) {             // issue k+1 loads; overlap with MFMAs below
            a0 = *(const bf16x8*)(ap + k0 + 32);
            a1 = *(const bf16x8*)(ap + k0 + 40);
            if constexpr (BN == 128) {
                b0 = *(const bf16x8*)(bp + k0 + 32);
                b1 = *(const bf16x8*)(bp + k0 + 40);
            } else {
                b0 = *(const bf16x8*)(bp + k0 + 32);
            }
        }
        bf16x8 af[4], bfr[NTW];
#pragma unroll
        for (int i = 0; i < 4; ++i) af[i] = *(const bf16x8*)&As[a_base + i * 16 * LP];
#pragma unroll
        for (int i = 0; i < NTW; ++i) bfr[i] = *(const bf16x8*)&Bs[b_base + i * 16 * LP];
#pragma unroll
        for (int mt = 0; mt < 4; ++mt)
#pragma unroll
            for (int nt = 0; nt < NTW; ++nt)
                acc[mt][nt] = __builtin_amdgcn_mfma_f32_16x16x32_bf16(af[mt], bfr[nt], acc[mt][nt], 0, 0, 0);
    }

#pragma unroll
    for (int mt = 0; mt < 4; ++mt) {
        int gmb = m0 + wm * 64 + mt * 16 + quad * 4;
#pragma unroll
        for (int nt = 0; nt < NTW; ++nt) {
            int gn = n0 + wn * (BN / 2) + nt * 16 + lc;
            float bv = bias[gn];
#pragma unroll
            for (int r = 0; r < 4; ++r) {
                int gm = gmb + r;
                if (gm >= Mrows) continue;
                float v = acc[mt][nt][r] + bv;
                if (ACT == 1) v = gelu_f(v);
                if (OMODE == 0) {
                    ((__bf16*)Cv)[(size_t)gm * ldc + gn] = (__bf16)v;
                } else {
                    float* cp = (float*)Cv + (size_t)gm * ldc + gn;
                    *cp = v + *cp;
                }
            }
        }
    }
}

// ---------------- MFMA attention on bf16 qkv; O -> compact bf16 buffer ----------------
constexpr int PPITCH = 280;
__global__ __launch_bounds__(256, 2) void attn_mfma(const __bf16* __restrict__ qkvb,
                                                    __bf16* __restrict__ obuf) {
    __shared__ __bf16 Vt[32][PPITCH];        // Vt[d][key], keys 257..271 zeroed
    __shared__ __bf16 Pb[4][16][PPITCH];     // per-wave unnormalized P
    int bb = blockIdx.x;
    int b = bb >> 3, h = bb & 7;
    int t = threadIdx.x;
    int w = t >> 6, L = t & 63;
    int c = L & 15, quad = L >> 4;
    const float scale = 0.17677669529663687f;  // 1/sqrt(32)
    const __bf16* qb = qkvb + (size_t)(b * SEQ) * 768 + h * 32;
    const __bf16* kb = qb + 256;
    const __bf16* vb = qb + 512;
    __bf16* ob = obuf + (size_t)(b * SEQ) * 256 + h * 32;

    // stage V^T (vector load, scalar transpose-store)
    for (int idx = t; idx < 272 * 4; idx += 256) {
        int key = idx >> 2, dc = (idx & 3) * 8;
        bf16x8 vv = {};
        if (key < SEQ) vv = *(const bf16x8*)(vb + (size_t)key * 768 + dc);
#pragma unroll
        for (int j = 0; j < 8; ++j) Vt[dc + j][key] = vv[j];
    }
    __syncthreads();

#pragma unroll 1
    for (int qt = 0; qt < 5; ++qt) {
        int q0 = qt * 64 + w * 16;
        if (q0 > 256) continue;
        int ntiles = (qt == 0 && w == 0) ? 17 : (qt * 4 + w + 1);
        if (ntiles > 17) ntiles = 17;
        int nkc = (ntiles + 1) >> 1;

        // Q fragment
        bf16x8 qf;
        {
            int qr = q0 + c; if (qr > 256) qr = 256;
            qf = *(const bf16x8*)(qb + (size_t)qr * 768 + quad * 8);
        }

        // QK^T
        f32x4 acc[17];
#pragma unroll
        for (int tt = 0; tt < 17; ++tt) {
            if (tt >= ntiles) continue;
            int kr = tt * 16 + c; if (kr > 256) kr = 256;
            bf16x8 kf = *(const bf16x8*)(kb + (size_t)kr * 768 + quad * 8);
            f32x4 z = {0.f, 0.f, 0.f, 0.f};
            acc[tt] = __builtin_amdgcn_mfma_f32_16x16x32_bf16(qf, kf, z, 0, 0, 0);
        }

        // masked softmax in C-layout
        float inv[4];
#pragma unroll
        for (int j = 0; j < 4; ++j) {
            int q = q0 + quad * 4 + j;
            float mx = -3.0e38f;
#pragma unroll
            for (int tt = 0; tt < 17; ++tt) {
                if (tt >= ntiles) continue;
                int key = tt * 16 + c;
                bool ok = (key < SEQ) && (q == 0 || key <= q);
                float v = ok ? acc[tt][j] * scale : -3.0e38f;
                mx = fmaxf(mx, v);
            }
            mx = fmaxf(mx, __shfl_xor(mx, 1));
            mx = fmaxf(mx, __shfl_xor(mx, 2));
            mx = fmaxf(mx, __shfl_xor(mx, 4));
            mx = fmaxf(mx, __shfl_xor(mx, 8));
            float s = 0.f;
#pragma unroll
            for (int tt = 0; tt < 17; ++tt) {
                if (tt >= ntiles) continue;
                int key = tt * 16 + c;
                bool ok = (key < SEQ) && (q == 0 || key <= q);
                float pv = ok ? expf(acc[tt][j] * scale - mx) : 0.f;
                s += pv;
                Pb[w][quad * 4 + j][key] = (__bf16)pv;
            }
            if ((ntiles & 1) && ntiles < 17)
                Pb[w][quad * 4 + j][ntiles * 16 + c] = (__bf16)0.f;
            s += __shfl_xor(s, 1);
            s += __shfl_xor(s, 2);
            s += __shfl_xor(s, 4);
            s += __shfl_xor(s, 8);
            inv[j] = 1.0f / s;
        }

        // PV
        f32x4 oacc0 = {0.f, 0.f, 0.f, 0.f};
        f32x4 oacc1 = {0.f, 0.f, 0.f, 0.f};
#pragma unroll
        for (int kc = 0; kc < 9; ++kc) {
            if (kc >= nkc) continue;
            int off = kc * 32 + quad * 8;
            bf16x8 af = {};
            bf16x8 bf0 = {};
            bf16x8 bf1 = {};
            if (off < 257) {
                af  = *(const bf16x8*)&Pb[w][c][off];
                bf0 = *(const bf16x8*)&Vt[c][off];
                bf1 = *(const bf16x8*)&Vt[16 + c][off];
            }
            oacc0 = __builtin_amdgcn_mfma_f32_16x16x32_bf16(af, bf0, oacc0, 0, 0, 0);
            oacc1 = __builtin_amdgcn_mfma_f32_16x16x32_bf16(af, bf1, oacc1, 0, 0, 0);
        }

        // epilogue: apply 1/sum, write bf16 O
#pragma unroll
        for (int j = 0; j < 4; ++j) {
            int q = q0 + quad * 4 + j;
            if (q < SEQ) {
                __bf16* op = ob + (size_t)q * 256;
                op[c]      = (__bf16)(oacc0[j] * inv[j]);
                op[16 + c] = (__bf16)(oacc1[j] * inv[j]);
            }
        }
    }
}

// ---------------- fp32 tiled GEMM (kept for GCN projection) ----------------
template <int ACT, bool RESID, bool REMAP>
__global__ __launch_bounds__(256) void gemm_std(const float* __restrict__ A, int lda,
                                                const float* __restrict__ Bw, int ldb,
                                                const float* __restrict__ bias,
                                                float* __restrict__ C, int ldc, int Ktot) {
    int t = threadIdx.x;
    int m0 = blockIdx.x << 6, n0 = blockIdx.y << 6;
    __shared__ float As[16][68];
    __shared__ float Bs[16][64];
    int arow = t >> 2, akk = (t & 3) << 2;
    int bk = t >> 4, bn = (t & 15) << 2;
    int tm = (t >> 4) << 2, tn = (t & 15) << 2;
    float acc[4][4] = {};
    const float* ap = A + (size_t)(m0 + arow) * lda + akk;
    const float* bp = Bw + (size_t)bk * ldb + n0 + bn;
    for (int k0 = 0; k0 < Ktot; k0 += 16) {
        float4 av = *(const float4*)(ap + k0);
        float4 bv = *(const float4*)(bp + (size_t)k0 * ldb);
        __syncthreads();
        As[akk + 0][arow] = av.x; As[akk + 1][arow] = av.y;
        As[akk + 2][arow] = av.z; As[akk + 3][arow] = av.w;
        *(float4*)&Bs[bk][bn] = bv;
        __syncthreads();
#pragma unroll
        for (int k = 0; k < 16; ++k) {
            float4 a = *(const float4*)&As[k][tm];
            float4 b = *(const float4*)&Bs[k][tn];
            acc[0][0] += a.x * b.x; acc[0][1] += a.x * b.y; acc[0][2] += a.x * b.z; acc[0][3] += a.x * b.w;
            acc[1][0] += a.y * b.x; acc[1][1] += a.y * b.y; acc[1][2] += a.y * b.z; acc[1][3] += a.y * b.w;
            acc[2][0] += a.z * b.x; acc[2][1] += a.z * b.y; acc[2][2] += a.z * b.z; acc[2][3] += a.z * b.w;
            acc[3][0] += a.w * b.x; acc[3][1] += a.w * b.y; acc[3][2] += a.w * b.z; acc[3][3] += a.w * b.w;
        }
    }
#pragma unroll
    for (int i = 0; i < 4; ++i) {
        int gm = m0 + tm + i;
        int orow = REMAP ? (gm + (gm >> 8) + 1) : gm;  // node -> xd row (skip cls slots)
        float* cp = C + (size_t)orow * ldc + n0 + tn;
        float4 r;
        r.x = acc[i][0] + bias[n0 + tn + 0];
        r.y = acc[i][1] + bias[n0 + tn + 1];
        r.z = acc[i][2] + bias[n0 + tn + 2];
        r.w = acc[i][3] + bias[n0 + tn + 3];
        if (ACT == 1) { r.x = gelu_f(r.x); r.y = gelu_f(r.y); r.z = gelu_f(r.z); r.w = gelu_f(r.w); }
        if (ACT == 2) { r.x = fmaxf(r.x, 0.f); r.y = fmaxf(r.y, 0.f); r.z = fmaxf(r.z, 0.f); r.w = fmaxf(r.w, 0.f); }
        if (RESID) {
            float4 o = *(const float4*)cp;
            r.x += o.x; r.y += o.y; r.z += o.z; r.w += o.w;
        }
        *(float4*)cp = r;
    }
}

// ---------------- decoder FC: grid (sample, out-chunk), 4 waves split K ----------------
template <int K, int NOUT>
__global__ __launch_bounds__(256) void dec_fc2(const float* __restrict__ in, const float* __restrict__ w,
                                               const float* __restrict__ bia, float* __restrict__ out) {
    __shared__ float rowbuf[K];
    __shared__ float part[4][64];
    int b = blockIdx.x, c = blockIdx.y, t = threadIdx.x;
    for (int i = t; i < K; i += 256) rowbuf[i] = in[(size_t)b * K + i];
    __syncthreads();
    int lane = t & 63, wv = t >> 6;
    int n = c * 64 + lane;
    const int KQ = K / 4;
    const float* wp = w + (size_t)(wv * KQ) * NOUT + n;
    float s = 0.f;
#pragma unroll 8
    for (int k = 0; k < KQ; ++k) s += rowbuf[wv * KQ + k] * wp[(size_t)k * NOUT];
    part[wv][lane] = s;
    __syncthreads();
    if (wv == 0) {
        float r = part[0][lane] + part[1][lane] + part[2][lane] + part[3][lane] + bia[n];
        out[(size_t)b * NOUT + n] = fmaxf(r, 0.f);
    }
}

// ---------------- launch ----------------
extern "C" void kernel_launch(void* const* d_in, const int* in_sizes, int n_in,
                              void* d_out, int out_size, void* d_ws, size_t ws_size,
                              hipStream_t stream) {
    const float* x         = (const float*)d_in[0];
    const float* p         = (const float*)d_in[1];
    const int*   ei        = (const int*)d_in[2];
    const float* gcn_w     = (const float*)d_in[4];
    const float* gcn_b     = (const float*)d_in[5];
    const float* cls_tok   = (const float*)d_in[6];
    const float* ln_pre_s  = (const float*)d_in[7];
    const float* ln_pre_b  = (const float*)d_in[8];
    const float* norm1_s   = (const float*)d_in[9];
    const float* norm1_b   = (const float*)d_in[10];
    const float* in_proj_w = (const float*)d_in[11];
    const float* in_proj_b = (const float*)d_in[12];
    const float* out_proj_w= (const float*)d_in[13];
    const float* out_proj_b= (const float*)d_in[14];
    const float* norm2_s   = (const float*)d_in[15];
    const float* norm2_b   = (const float*)d_in[16];
    const float* ff_w1     = (const float*)d_in[17];
    const float* ff_b1     = (const float*)d_in[18];
    const float* ff_w2     = (const float*)d_in[19];
    const float* ff_b2     = (const float*)d_in[20];
    const float* ln_post_s = (const float*)d_in[21];
    const float* ln_post_b = (const float*)d_in[22];
    const float* dec_w1    = (const float*)d_in[23];
    const float* dec_b1    = (const float*)d_in[24];
    const float* dec_w2    = (const float*)d_in[25];
    const float* dec_b2    = (const float*)d_in[26];
    const float* dec_w3    = (const float*)d_in[27];
    const float* dec_b3    = (const float*)d_in[28];

    float* ws   = (float*)d_ws;
    float* y    = ws + F_Y;
    float* agg  = ws + F_AGG;
    float* xd   = ws + F_XD;
    float* cls  = ws + F_CLS;
    float* dd1  = ws + F_D1;
    float* dd2  = ws + F_D2;
    float* wpad = ws + F_WPAD;
    float* dinv = ws + F_DINV;
    int* ibase  = (int*)(ws + F_IEND);
    int* indeg  = ibase;
    int* offs   = ibase + N_NODES;
    int* cursor = offs + N_NODES + 1;
    int* csr    = cursor + N_NODES;
    uintptr_t ub = ((uintptr_t)(csr + NEDGE) + 15) & ~(uintptr_t)15;
    __bf16* h1b  = (__bf16*)ub;                          // [MROWS,256] (also attention O)
    __bf16* qkvb = h1b  + (size_t)MROWS * 256;           // [MROWS,768]
    __bf16* ffbb = qkvb + (size_t)MROWS * 768;           // [MROWS,1024]
    __bf16* wt_in  = ffbb  + (size_t)MROWS * 1024;       // 2 x 768*256
    __bf16* wt_out = wt_in  + 2 * 768 * 256;             // 2 x 256*256
    __bf16* wt_f1  = wt_out + 2 * 256 * 256;             // 2 x 1024*256
    __bf16* wt_f2  = wt_f1  + 2 * 1024 * 256;            // 2 x 256*1024

    // GCN prelude
    hipMemsetAsync(indeg, 0, N_NODES * sizeof(int), stream);
    hist_kernel<<<NEDGE / 256, 256, 0, stream>>>(ei + NEDGE, indeg);
    scan_kernel<<<1, 1024, 0, stream>>>(indeg, offs, cursor, dinv);
    fill_kernel<<<NEDGE / 256, 256, 0, stream>>>(ei, cursor, csr);
    y_kernel<<<N_NODES * 64 / 256, 256, 0, stream>>>(x, p, dinv, y);
    agg_kernel<<<N_NODES / 4, 256, 0, stream>>>(y, dinv, offs, csr, agg);
    wpad_kernel<<<64, 256, 0, stream>>>(gcn_w, wpad);

    // weight transpose+cast (once per call)
    for (int l = 0; l < 2; ++l) {
        tcast_kernel<<<dim3(4, 12), 256, 0, stream>>>(in_proj_w + (size_t)l * 256 * 768,
                                                      wt_in + (size_t)l * 768 * 256, 256, 768);
        tcast_kernel<<<dim3(4, 4), 256, 0, stream>>>(out_proj_w + (size_t)l * 256 * 256,
                                                     wt_out + (size_t)l * 256 * 256, 256, 256);
        tcast_kernel<<<dim3(4, 16), 256, 0, stream>>>(ff_w1 + (size_t)l * 256 * 1024,
                                                      wt_f1 + (size_t)l * 1024 * 256, 256, 1024);
        tcast_kernel<<<dim3(16, 4), 256, 0, stream>>>(ff_w2 + (size_t)l * 1024 * 256,
                                                      wt_f2 + (size_t)l * 256 * 1024, 1024, 256);
    }

    // GCN matmul -> xd rows (remapped past cls slots), fp32
    gemm_std<0, false, true><<<dim3(256, 4), 256, 0, stream>>>(agg, 64, wpad, 256, gcn_b, xd, 256, 64);
    cls_write<<<64, 256, 0, stream>>>(cls_tok, xd);
    ln4_kernel<0><<<MROWS / 4, 256, 0, stream>>>(xd, 256, xd, ln_pre_s, ln_pre_b);

    const int MB = (MROWS + 127) / 128;            // 129
    const int MG8 = (MB + 7) / 8;                  // 17 swizzle groups
    for (int l = 0; l < 2; ++l) {
        ln4_kernel<1><<<MROWS / 4, 256, 0, stream>>>(xd, 256, h1b, norm1_s + l * WDIM, norm1_b + l * WDIM);
        gemm_bf<128, 0, 0><<<8 * 6 * MG8, 256, 0, stream>>>(
            h1b, 256, wt_in + (size_t)l * 768 * 256, in_proj_b + l * 768, qkvb, 768, 256, MROWS, MB, 6);
        attn_mfma<<<512, 256, 0, stream>>>(qkvb, h1b);
        gemm_bf<64, 0, 1><<<8 * 4 * MG8, 256, 0, stream>>>(
            h1b, 256, wt_out + (size_t)l * 256 * 256, out_proj_b + l * WDIM, xd, 256, 256, MROWS, MB, 4);
        ln4_kernel<1><<<MROWS / 4, 256, 0, stream>>>(xd, 256, h1b, norm2_s + l * WDIM, norm2_b + l * WDIM);
        gemm_bf<128, 1, 0><<<8 * 8 * MG8, 256, 0, stream>>>(
            h1b, 256, wt_f1 + (size_t)l * 1024 * 256, ff_b1 + l * DFF, ffbb, 1024, 256, MROWS, MB, 8);
        gemm_bf<64, 1, 1><<<8 * 4 * MG8, 256, 0, stream>>>(
            ffbb, 1024, wt_f2 + (size_t)l * 256 * 1024, ff_b2 + l * WDIM, xd, 256, 1024, MROWS, MB, 4);
    }

    // cls extract + ln_post + decoder
    ln4_kernel<0><<<BGRAPH / 4, 256, 0, stream>>>(xd, SEQ * WDIM, cls, ln_post_s, ln_post_b);
    dec_fc2<256, 512><<<dim3(BGRAPH, 8), 256, 0, stream>>>(cls, dec_w1, dec_b1, dd1);
    dec_fc2<512, 512><<<dim3(BGRAPH, 8), 256, 0, stream>>>(dd1, dec_w2, dec_b2, dd2);
    dec_fc2<512, 64><<<dim3(BGRAPH, 1), 256, 0, stream>>>(dd2, dec_w3, dec_b3, (float*)d_out);
}